// Round 1
// baseline (313.266 us; speedup 1.0000x reference)
//
#include <hip/hip_runtime.h>

#define N_SEQ 4096
#define N_FFT 8192
#define NBUT  (N_FFT/2)   // butterflies per stage
#define LAYERS 3

// ---------------- RPE MLP: a_t[(h*64+d)][pos], pos in [0,8192) ----------------
__global__ __launch_bounds__(256) void rpe_kernel(
    const float* __restrict__ w_in, const float* __restrict__ b_in,
    const float* __restrict__ w_hid, const float* __restrict__ b_hid,
    const float* __restrict__ w_out, const float* __restrict__ b_out,
    float* __restrict__ a_t)
{
    __shared__ float tile[512][16];
    const int tid  = threadIdx.x;
    const int lane = tid & 63;
    const int wave = tid >> 6;
    const int p0   = blockIdx.x * 16;

    for (int pi = 0; pi < 4; ++pi) {
        const int pl = wave * 4 + pi;
        const int p  = p0 + pl;
        float v;
        if (p == 0 || p == N_SEQ) v = 1.0f;                       // zero_idx slots
        else if (p < N_SEQ)       v = 1.0f / (float)(p + 1);      // pos_idx
        else                      v = -1.0f / (float)(2*N_SEQ + 1 - p); // neg_idx

        float h = v * w_in[lane] + b_in[lane];
        for (int L = 0; L < LAYERS; ++L) {
            float s = h * h;
            for (int off = 32; off > 0; off >>= 1) s += __shfl_xor(s, off);
            float r = rsqrtf(s * (1.0f/64.0f) + 1e-8f);
            float u = fmaxf(h * r, 0.0f);
            float acc = b_hid[L*64 + lane];
            for (int j = 0; j < 64; ++j)
                acc = fmaf(__shfl(u, j), w_hid[L*4096 + j*64 + lane], acc);
            h = acc;
        }
        float s = h * h;
        for (int off = 32; off > 0; off >>= 1) s += __shfl_xor(s, off);
        float r = rsqrtf(s * (1.0f/64.0f) + 1e-8f);
        float u = fmaxf(h * r, 0.0f);
        for (int c = 0; c < 8; ++c) {
            float acc = b_out[c*64 + lane];
            for (int j = 0; j < 64; ++j)
                acc = fmaf(__shfl(u, j), w_out[j*512 + c*64 + lane], acc);
            tile[c*64 + lane][pl] = acc;   // feature e=c*64+lane -> row h*64+d
        }
    }
    __syncthreads();
    // 512 rows x 16 floats -> full 64B-line writes
    for (int it = 0; it < 8; ++it) {
        int idx4 = it*256 + tid;
        int e = idx4 >> 2, q = idx4 & 3;
        float4 val = *(const float4*)&tile[e][q*4];
        *(float4*)&a_t[(size_t)e * N_FFT + p0 + q*4] = val;
    }
}

// ---------------- radix-2 FFT helpers (LDS-resident, 256 threads) ----------------
// forward DIF: natural-in, bit-reversed-out, twiddle e^{-i}
__device__ inline void fft_dif(float* re, float* im, int tid)
{
    for (int s = 13; s >= 1; --s) {
        const int half = 1 << (s - 1);
        const float w = -6.283185307179586f / (float)(1 << s);
        for (int k = tid; k < NBUT; k += 256) {
            int j  = k & (half - 1);
            int i0 = ((k >> (s - 1)) << s) | j;
            int i1 = i0 + half;
            float ur = re[i0], ui = im[i0];
            float vr = re[i1], vi = im[i1];
            re[i0] = ur + vr; im[i0] = ui + vi;
            float tr = ur - vr, ti = ui - vi;
            float c, sn;
            __sincosf(w * (float)j, &sn, &c);
            re[i1] = tr * c - ti * sn;
            im[i1] = tr * sn + ti * c;
        }
        __syncthreads();
    }
}

// inverse DIT: bit-reversed-in, natural-out, twiddle e^{+i}, unscaled
__device__ inline void fft_dit_inv(float* re, float* im, int tid)
{
    for (int s = 1; s <= 13; ++s) {
        const int half = 1 << (s - 1);
        const float w = 6.283185307179586f / (float)(1 << s);
        for (int k = tid; k < NBUT; k += 256) {
            int j  = k & (half - 1);
            int i0 = ((k >> (s - 1)) << s) | j;
            int i1 = i0 + half;
            float c, sn;
            __sincosf(w * (float)j, &sn, &c);
            float xr = re[i1], xi = im[i1];
            float vr = xr * c - xi * sn;
            float vi = xr * sn + xi * c;
            float ur = re[i0], ui = im[i0];
            re[i0] = ur + vr; im[i0] = ui + vi;
            re[i1] = ur - vr; im[i1] = ui - vi;
        }
        __syncthreads();
    }
}

// ---------------- FFT of kernel a: Af[hd][0..8191] (bitrev DIF order) ----------------
__global__ __launch_bounds__(256) void fft_a_kernel(const float* __restrict__ a_t,
                                                    float2* __restrict__ Af)
{
    __shared__ float re[N_FFT];
    __shared__ float im[N_FFT];
    const int tid = threadIdx.x;
    const size_t row = blockIdx.x;  // h*64+d
    const float* src = a_t + row * N_FFT;
    for (int i = tid; i < N_FFT; i += 256) { re[i] = src[i]; im[i] = 0.0f; }
    __syncthreads();
    fft_dif(re, im, tid);
    float2* dst = Af + row * N_FFT;
    for (int i = tid; i < N_FFT; i += 256) dst[i] = make_float2(re[i], im[i]);
}

// ---------------- transpose x: (BH, N, D) -> (BH, D, N) ----------------
__global__ __launch_bounds__(256) void transpose_x_kernel(const float* __restrict__ x,
                                                          float* __restrict__ xt)
{
    __shared__ float t[64][65];
    int bh = blockIdx.x >> 6;
    int tn = blockIdx.x & 63;
    int lx = threadIdx.x & 63;
    int ly = threadIdx.x >> 6;
    const float* src = x + ((size_t)bh * N_SEQ + tn * 64) * 64;
    for (int r = ly; r < 64; r += 4)
        t[r][lx] = src[r * 64 + lx];       // (pos=tn*64+r, d=lx)
    __syncthreads();
    float* dst = xt + (size_t)bh * 64 * N_SEQ + tn * 64;
    for (int r = ly; r < 64; r += 4)
        dst[(size_t)r * N_SEQ + lx] = t[lx][r];  // row d=r, col pos=tn*64+lx
}

// ---------------- conv: per (b,h,d) row, FFT -> mult -> iFFT ----------------
__global__ __launch_bounds__(256) void conv_kernel(const float* __restrict__ xt,
                                                   const float2* __restrict__ Af,
                                                   float* __restrict__ out_t)
{
    __shared__ float re[N_FFT];
    __shared__ float im[N_FFT];
    const int tid = threadIdx.x;
    const int row = blockIdx.x;   // b*512 + h*64 + d
    const int hd  = row & 511;
    const float* src = xt + (size_t)row * N_SEQ;
    for (int i = tid; i < N_SEQ; i += 256) {
        re[i] = src[i];        im[i] = 0.0f;
        re[i + N_SEQ] = 0.0f;  im[i + N_SEQ] = 0.0f;
    }
    __syncthreads();
    fft_dif(re, im, tid);
    const float2* af = Af + (size_t)hd * N_FFT;
    const float inv = 1.0f / (float)N_FFT;
    for (int i = tid; i < N_FFT; i += 256) {
        float2 a = af[i];
        float xr = re[i], xi = im[i];
        re[i] = (xr * a.x - xi * a.y) * inv;
        im[i] = (xr * a.y + xi * a.x) * inv;
    }
    __syncthreads();
    fft_dit_inv(re, im, tid);
    float* dst = out_t + (size_t)row * N_SEQ;
    for (int i = tid; i < N_SEQ; i += 256) dst[i] = re[i];
}

// ---------------- transpose out: (BH, D, N) -> (BH, N, D) ----------------
__global__ __launch_bounds__(256) void transpose_o_kernel(const float* __restrict__ out_t,
                                                          float* __restrict__ out)
{
    __shared__ float t[64][65];
    int bh = blockIdx.x >> 6;
    int tn = blockIdx.x & 63;
    int lx = threadIdx.x & 63;
    int ly = threadIdx.x >> 6;
    const float* src = out_t + (size_t)bh * 64 * N_SEQ + tn * 64;
    for (int r = ly; r < 64; r += 4)
        t[r][lx] = src[(size_t)r * N_SEQ + lx];  // (d=r, pos=tn*64+lx)
    __syncthreads();
    float* dst = out + ((size_t)bh * N_SEQ + tn * 64) * 64;
    for (int r = ly; r < 64; r += 4)
        dst[r * 64 + lx] = t[lx][r];             // (pos=tn*64+r, d=lx)
}

extern "C" void kernel_launch(void* const* d_in, const int* in_sizes, int n_in,
                              void* d_out, int out_size, void* d_ws, size_t ws_size,
                              hipStream_t stream)
{
    const float* x     = (const float*)d_in[0];
    const float* w_in  = (const float*)d_in[1];
    const float* b_in  = (const float*)d_in[2];
    const float* w_hid = (const float*)d_in[3];
    const float* b_hid = (const float*)d_in[4];
    const float* w_out = (const float*)d_in[5];
    const float* b_out = (const float*)d_in[6];
    float* out = (float*)d_out;

    char* ws = (char*)d_ws;
    float2* Af   = (float2*)ws;                               // 32 MB: 512 x 8192 cplx
    float*  xt   = (float*)(ws + (size_t)32 * 1024 * 1024);   // 16 MB: 16 x 64 x 4096
    float*  a_t  = (float*)(ws + (size_t)48 * 1024 * 1024);   // 16 MB (reused as out_t)
    float*  out_t = a_t;  // safe: fft_a consumes a_t before conv writes (stream order)

    rpe_kernel<<<512, 256, 0, stream>>>(w_in, b_in, w_hid, b_hid, w_out, b_out, a_t);
    fft_a_kernel<<<512, 256, 0, stream>>>(a_t, Af);
    transpose_x_kernel<<<1024, 256, 0, stream>>>(x, xt);
    conv_kernel<<<1024, 256, 0, stream>>>(xt, Af, out_t);
    transpose_o_kernel<<<1024, 256, 0, stream>>>(out_t, out);
}

// Round 2
// 220.208 us; speedup vs baseline: 1.4226x; 1.4226x over previous
//
#include <hip/hip_runtime.h>

#define N_SEQ 4096
#define N_FFT 8192
#define LAYERS 3

// ================= radix-4 FFT (LDS-resident, 256 threads) =================
// forward DIF: natural-in, digit-reversed-out, e^{-i} twiddles.
// 6 radix-4 stages (m=8192..8) + final trivial radix-2.
__device__ inline void fft_dif_r4(float* re, float* im, int tid)
{
    for (int mshift = 13; mshift >= 3; mshift -= 2) {
        const int q = 1 << (mshift - 2);
        const float wstep = -6.283185307179586f / (float)(1 << mshift);
        for (int k = tid; k < 2048; k += 256) {
            int j = k & (q - 1);
            int g = k >> (mshift - 2);
            int i0 = (g << mshift) | j;
            int i1 = i0 + q, i2 = i1 + q, i3 = i2 + q;
            float x0r = re[i0], x0i = im[i0], x1r = re[i1], x1i = im[i1];
            float x2r = re[i2], x2i = im[i2], x3r = re[i3], x3i = im[i3];
            float ar = x0r + x2r, ai = x0i + x2i;
            float br = x0r - x2r, bi = x0i - x2i;
            float cr = x1r + x3r, ci = x1i + x3i;
            float dr = x1i - x3i, di = -(x1r - x3r);    // d = -i*(x1-x3)
            re[i0] = ar + cr; im[i0] = ai + ci;
            float c1, s1; __sincosf(wstep * (float)j, &s1, &c1);  // W^j
            float c2 = c1 * c1 - s1 * s1, s2 = 2.f * c1 * s1;     // W^2j
            float c3 = c2 * c1 - s2 * s1, s3 = c2 * s1 + s2 * c1; // W^3j
            float t1r = br + dr, t1i = bi + di;
            re[i1] = t1r * c1 - t1i * s1; im[i1] = t1r * s1 + t1i * c1;
            float t2r = ar - cr, t2i = ai - ci;
            re[i2] = t2r * c2 - t2i * s2; im[i2] = t2r * s2 + t2i * c2;
            float t3r = br - dr, t3i = bi - di;
            re[i3] = t3r * c3 - t3i * s3; im[i3] = t3r * s3 + t3i * c3;
        }
        __syncthreads();
    }
    for (int k = tid; k < 4096; k += 256) {   // radix-2, m=2, W^0=1
        int i0 = k << 1, i1 = i0 + 1;
        float ur = re[i0], ui = im[i0], vr = re[i1], vi = im[i1];
        re[i0] = ur + vr; im[i0] = ui + vi;
        re[i1] = ur - vr; im[i1] = ui - vi;
    }
    __syncthreads();
}

// inverse (adjoint chain, unscaled): digit-reversed-in, natural-out, e^{+i}.
__device__ inline void fft_dit_inv_r4(float* re, float* im, int tid)
{
    for (int k = tid; k < 4096; k += 256) {   // undo radix-2 first
        int i0 = k << 1, i1 = i0 + 1;
        float ur = re[i0], ui = im[i0], vr = re[i1], vi = im[i1];
        re[i0] = ur + vr; im[i0] = ui + vi;
        re[i1] = ur - vr; im[i1] = ui - vi;
    }
    __syncthreads();
    for (int mshift = 3; mshift <= 13; mshift += 2) {
        const int q = 1 << (mshift - 2);
        const float wstep = 6.283185307179586f / (float)(1 << mshift);
        for (int k = tid; k < 2048; k += 256) {
            int j = k & (q - 1);
            int g = k >> (mshift - 2);
            int i0 = (g << mshift) | j;
            int i1 = i0 + q, i2 = i1 + q, i3 = i2 + q;
            float c1, s1; __sincosf(wstep * (float)j, &s1, &c1);  // conj(W^j)
            float c2 = c1 * c1 - s1 * s1, s2 = 2.f * c1 * s1;
            float c3 = c2 * c1 - s2 * s1, s3 = c2 * s1 + s2 * c1;
            float t0r = re[i0], t0i = im[i0];
            float y1r = re[i1], y1i = im[i1];
            float y2r = re[i2], y2i = im[i2];
            float y3r = re[i3], y3i = im[i3];
            float t1r = y1r * c1 - y1i * s1, t1i = y1r * s1 + y1i * c1;
            float t2r = y2r * c2 - y2i * s2, t2i = y2r * s2 + y2i * c2;
            float t3r = y3r * c3 - y3i * s3, t3i = y3r * s3 + y3i * c3;
            float pr = t0r + t2r, pi = t0i + t2i;
            float qr = t0r - t2r, qi = t0i - t2i;
            float rr = t1r + t3r, ri = t1i + t3i;
            float sr = -(t1i - t3i), si = t1r - t3r;  // s = i*(t1-t3)
            re[i0] = pr + rr; im[i0] = pi + ri;
            re[i1] = qr + sr; im[i1] = qi + si;
            re[i2] = pr - rr; im[i2] = pi - ri;
            re[i3] = qr - sr; im[i3] = qi - si;
        }
        __syncthreads();
    }
}

// ================= RPE MLP: a_t[e][pos], e = h*64+d =================
__global__ __launch_bounds__(256) void rpe_kernel(
    const float* __restrict__ w_in, const float* __restrict__ b_in,
    const float* __restrict__ w_hid, const float* __restrict__ b_hid,
    const float* __restrict__ w_out, const float* __restrict__ b_out,
    float* __restrict__ a_t)
{
    __shared__ float hbuf[32][65];    // [pos][feat], pad -> (p+j)%32 banks, 2-way free
    __shared__ float wtile[64][64];   // wave-uniform broadcast reads
    __shared__ float sums[32][8];
    const int tid = threadIdx.x;
    const int p = tid & 31;
    const int g = tid >> 5;           // 8 groups x 8 features
    const int pg = blockIdx.x * 32 + p;

    float v;
    if (pg == 0 || pg == N_SEQ) v = 1.0f;
    else if (pg < N_SEQ)        v = 1.0f / (float)(pg + 1);
    else                        v = -1.0f / (float)(2 * N_SEQ + 1 - pg);

    float h[8];
    for (int fi = 0; fi < 8; ++fi) {
        int f = g * 8 + fi;
        h[fi] = v * w_in[f] + b_in[f];
    }

    for (int L = 0; L < LAYERS; ++L) {
        float s = 0.f;
        for (int fi = 0; fi < 8; ++fi) s += h[fi] * h[fi];
        sums[p][g] = s;
        __syncthreads();
        float tot = 0.f;
        for (int gg = 0; gg < 8; ++gg) tot += sums[p][gg];
        float r = rsqrtf(tot * (1.0f / 64.0f) + 1e-8f);
        for (int fi = 0; fi < 8; ++fi)
            hbuf[p][g * 8 + fi] = fmaxf(h[fi] * r, 0.0f);
        for (int i = tid; i < 4096; i += 256)
            wtile[i >> 6][i & 63] = w_hid[L * 4096 + i];
        __syncthreads();
        for (int fi = 0; fi < 8; ++fi) h[fi] = b_hid[L * 64 + g * 8 + fi];
        for (int j = 0; j < 64; ++j) {
            float u = hbuf[p][j];
            for (int fi = 0; fi < 8; ++fi)
                h[fi] = fmaf(u, wtile[j][g * 8 + fi], h[fi]);
        }
        __syncthreads();   // before sums/hbuf/wtile rewritten
    }
    {
        float s = 0.f;
        for (int fi = 0; fi < 8; ++fi) s += h[fi] * h[fi];
        sums[p][g] = s;
        __syncthreads();
        float tot = 0.f;
        for (int gg = 0; gg < 8; ++gg) tot += sums[p][gg];
        float r = rsqrtf(tot * (1.0f / 64.0f) + 1e-8f);
        for (int fi = 0; fi < 8; ++fi)
            hbuf[p][g * 8 + fi] = fmaxf(h[fi] * r, 0.0f);
        __syncthreads();
    }
    // output layer: 8 chunks of 64 features
    for (int c = 0; c < 8; ++c) {
        for (int i = tid; i < 4096; i += 256)
            wtile[i >> 6][i & 63] = w_out[(i >> 6) * 512 + c * 64 + (i & 63)];
        __syncthreads();
        float acc[8];
        for (int fi = 0; fi < 8; ++fi) acc[fi] = b_out[c * 64 + g * 8 + fi];
        for (int j = 0; j < 64; ++j) {
            float u = hbuf[p][j];
            for (int fi = 0; fi < 8; ++fi)
                acc[fi] = fmaf(u, wtile[j][g * 8 + fi], acc[fi]);
        }
        for (int fi = 0; fi < 8; ++fi) {
            int e = c * 64 + g * 8 + fi;
            a_t[(size_t)e * N_FFT + pg] = acc[fi];
        }
        __syncthreads();   // before wtile overwrite
    }
}

// ================= FFT of kernel a -> Af (digit-reversed order) =================
__global__ __launch_bounds__(256) void fft_a_kernel(const float* __restrict__ a_t,
                                                    float2* __restrict__ Af)
{
    __shared__ float re[N_FFT];
    __shared__ float im[N_FFT];
    const int tid = threadIdx.x;
    const size_t row = blockIdx.x;  // hd
    const float* src = a_t + row * N_FFT;
    for (int i = tid; i < N_FFT; i += 256) { re[i] = src[i]; im[i] = 0.0f; }
    __syncthreads();
    fft_dif_r4(re, im, tid);
    float2* dst = Af + row * N_FFT;
    for (int i = tid; i < N_FFT; i += 256) dst[i] = make_float2(re[i], im[i]);
}

// ========== transpose x: (2,8,N,64) -> xt2[hd][n] = (x_b0, x_b1) ==========
__global__ __launch_bounds__(256) void transpose_x_kernel(const float* __restrict__ x,
                                                          float2* __restrict__ xt2)
{
    __shared__ float t0[64][65];
    __shared__ float t1[64][65];
    int h = blockIdx.x >> 6;
    int nb = blockIdx.x & 63;
    int lx = threadIdx.x & 63;
    int ly = threadIdx.x >> 6;
    const float* s0 = x + ((size_t)h * N_SEQ + nb * 64) * 64;
    const float* s1 = x + ((size_t)(8 + h) * N_SEQ + nb * 64) * 64;
    for (int r = ly; r < 64; r += 4) {
        t0[r][lx] = s0[r * 64 + lx];   // (n = nb*64+r, d = lx)
        t1[r][lx] = s1[r * 64 + lx];
    }
    __syncthreads();
    for (int r = ly; r < 64; r += 4) {
        float2* dst = xt2 + (size_t)(h * 64 + r) * N_SEQ + nb * 64;
        dst[lx] = make_float2(t0[lx][r], t1[lx][r]);
    }
}

// ========== conv: per hd row, packed-complex FFT -> mult -> iFFT ==========
__global__ __launch_bounds__(256) void conv_kernel(const float2* __restrict__ xt2,
                                                   const float2* __restrict__ Af,
                                                   float2* __restrict__ out_t2)
{
    __shared__ float re[N_FFT];
    __shared__ float im[N_FFT];
    const int tid = threadIdx.x;
    const int hd = blockIdx.x;   // 0..511
    const float2* src = xt2 + (size_t)hd * N_SEQ;
    for (int i = tid; i < N_SEQ; i += 256) {
        float2 v = src[i];
        re[i] = v.x; im[i] = v.y;          // z = x_b0 + i*x_b1
        re[i + N_SEQ] = 0.f; im[i + N_SEQ] = 0.f;
    }
    __syncthreads();
    fft_dif_r4(re, im, tid);
    const float2* af = Af + (size_t)hd * N_FFT;
    const float inv = 1.0f / (float)N_FFT;
    for (int i = tid; i < N_FFT; i += 256) {
        float2 a = af[i];
        float xr = re[i], xi = im[i];
        re[i] = (xr * a.x - xi * a.y) * inv;
        im[i] = (xr * a.y + xi * a.x) * inv;
    }
    __syncthreads();
    fft_dit_inv_r4(re, im, tid);
    float2* dst = out_t2 + (size_t)hd * N_SEQ;
    for (int i = tid; i < N_SEQ; i += 256) dst[i] = make_float2(re[i], im[i]);
}

// ========== transpose out: out_t2[hd][n] -> out (2,8,N,64) ==========
__global__ __launch_bounds__(256) void transpose_o_kernel(const float2* __restrict__ out_t2,
                                                          float* __restrict__ out)
{
    __shared__ float t0[64][65];
    __shared__ float t1[64][65];
    int h = blockIdx.x >> 6;
    int nb = blockIdx.x & 63;
    int lx = threadIdx.x & 63;
    int ly = threadIdx.x >> 6;
    for (int r = ly; r < 64; r += 4) {
        float2 v = out_t2[(size_t)(h * 64 + r) * N_SEQ + nb * 64 + lx];
        t0[r][lx] = v.x;   // (d = r, n = nb*64+lx)
        t1[r][lx] = v.y;
    }
    __syncthreads();
    float* d0 = out + ((size_t)h * N_SEQ + nb * 64) * 64;
    float* d1 = out + ((size_t)(8 + h) * N_SEQ + nb * 64) * 64;
    for (int r = ly; r < 64; r += 4) {
        d0[r * 64 + lx] = t0[lx][r];
        d1[r * 64 + lx] = t1[lx][r];
    }
}

extern "C" void kernel_launch(void* const* d_in, const int* in_sizes, int n_in,
                              void* d_out, int out_size, void* d_ws, size_t ws_size,
                              hipStream_t stream)
{
    const float* x     = (const float*)d_in[0];
    const float* w_in  = (const float*)d_in[1];
    const float* b_in  = (const float*)d_in[2];
    const float* w_hid = (const float*)d_in[3];
    const float* b_hid = (const float*)d_in[4];
    const float* w_out = (const float*)d_in[5];
    const float* b_out = (const float*)d_in[6];
    float* out = (float*)d_out;

    char* ws = (char*)d_ws;
    float2* Af    = (float2*)ws;                               // 32 MB: 512 x 8192 cplx
    float2* xt2   = (float2*)(ws + (size_t)32 * 1024 * 1024);  // 16 MB: 512 x 4096 pairs
    float*  a_t   = (float*)(ws + (size_t)48 * 1024 * 1024);   // 16 MB
    float2* out_t2 = (float2*)a_t;  // safe reuse: fft_a consumes a_t before conv writes

    rpe_kernel<<<256, 256, 0, stream>>>(w_in, b_in, w_hid, b_hid, w_out, b_out, a_t);
    fft_a_kernel<<<512, 256, 0, stream>>>(a_t, Af);
    transpose_x_kernel<<<512, 256, 0, stream>>>(x, xt2);
    conv_kernel<<<512, 256, 0, stream>>>(xt2, Af, out_t2);
    transpose_o_kernel<<<512, 256, 0, stream>>>(out_t2, out);
}

// Round 3
// 186.956 us; speedup vs baseline: 1.6756x; 1.1779x over previous
//
#include <hip/hip_runtime.h>

#define N_SEQ 4096
#define N_FFT 8192
#define LAYERS 3
#define FT 512   // threads per FFT block

// ================= radix-4 FFT pieces (LDS-resident, FT threads) =================
// Forward DIF, natural-in -> digit-reversed-out, e^{-i}. Stage m=8192 handled by
// callers (fused with load); here stages m=2048..8 then trivial radix-2.
__device__ inline void fft_dif_main(float* re, float* im, int tid)
{
    for (int mshift = 11; mshift >= 3; mshift -= 2) {
        const int q = 1 << (mshift - 2);
        const float wstep = -6.283185307179586f / (float)(1 << mshift);
        for (int k = tid; k < 2048; k += FT) {
            int j = k & (q - 1);
            int g = k >> (mshift - 2);
            int i0 = (g << mshift) | j;
            int i1 = i0 + q, i2 = i1 + q, i3 = i2 + q;
            float x0r = re[i0], x0i = im[i0], x1r = re[i1], x1i = im[i1];
            float x2r = re[i2], x2i = im[i2], x3r = re[i3], x3i = im[i3];
            float ar = x0r + x2r, ai = x0i + x2i;
            float br = x0r - x2r, bi = x0i - x2i;
            float cr = x1r + x3r, ci = x1i + x3i;
            float dr = x1i - x3i, di = -(x1r - x3r);
            re[i0] = ar + cr; im[i0] = ai + ci;
            float c1, s1; __sincosf(wstep * (float)j, &s1, &c1);
            float c2 = c1 * c1 - s1 * s1, s2 = 2.f * c1 * s1;
            float c3 = c2 * c1 - s2 * s1, s3 = c2 * s1 + s2 * c1;
            float t1r = br + dr, t1i = bi + di;
            re[i1] = t1r * c1 - t1i * s1; im[i1] = t1r * s1 + t1i * c1;
            float t2r = ar - cr, t2i = ai - ci;
            re[i2] = t2r * c2 - t2i * s2; im[i2] = t2r * s2 + t2i * c2;
            float t3r = br - dr, t3i = bi - di;
            re[i3] = t3r * c3 - t3i * s3; im[i3] = t3r * s3 + t3i * c3;
        }
        __syncthreads();
    }
    for (int k = tid; k < 4096; k += FT) {   // radix-2, m=2
        int i0 = k << 1, i1 = i0 + 1;
        float ur = re[i0], ui = im[i0], vr = re[i1], vi = im[i1];
        re[i0] = ur + vr; im[i0] = ui + vi;
        re[i1] = ur - vr; im[i1] = ui - vi;
    }
    __syncthreads();
}

// Inverse adjoint chain (unscaled), digit-reversed-in -> natural-out, e^{+i}.
// radix-2 first, then stages m=8..2048. Final m=8192 stage done by caller (fused store).
__device__ inline void fft_inv_main(float* re, float* im, int tid)
{
    for (int k = tid; k < 4096; k += FT) {
        int i0 = k << 1, i1 = i0 + 1;
        float ur = re[i0], ui = im[i0], vr = re[i1], vi = im[i1];
        re[i0] = ur + vr; im[i0] = ui + vi;
        re[i1] = ur - vr; im[i1] = ui - vi;
    }
    __syncthreads();
    for (int mshift = 3; mshift <= 11; mshift += 2) {
        const int q = 1 << (mshift - 2);
        const float wstep = 6.283185307179586f / (float)(1 << mshift);
        for (int k = tid; k < 2048; k += FT) {
            int j = k & (q - 1);
            int g = k >> (mshift - 2);
            int i0 = (g << mshift) | j;
            int i1 = i0 + q, i2 = i1 + q, i3 = i2 + q;
            float c1, s1; __sincosf(wstep * (float)j, &s1, &c1);
            float c2 = c1 * c1 - s1 * s1, s2 = 2.f * c1 * s1;
            float c3 = c2 * c1 - s2 * s1, s3 = c2 * s1 + s2 * c1;
            float t0r = re[i0], t0i = im[i0];
            float y1r = re[i1], y1i = im[i1];
            float y2r = re[i2], y2i = im[i2];
            float y3r = re[i3], y3i = im[i3];
            float t1r = y1r * c1 - y1i * s1, t1i = y1r * s1 + y1i * c1;
            float t2r = y2r * c2 - y2i * s2, t2i = y2r * s2 + y2i * c2;
            float t3r = y3r * c3 - y3i * s3, t3i = y3r * s3 + y3i * c3;
            float pr = t0r + t2r, pi = t0i + t2i;
            float qr = t0r - t2r, qi = t0i - t2i;
            float rr = t1r + t3r, ri = t1i + t3i;
            float sr = -(t1i - t3i), si = t1r - t3r;
            re[i0] = pr + rr; im[i0] = pi + ri;
            re[i1] = qr + sr; im[i1] = qi + si;
            re[i2] = pr - rr; im[i2] = pi - ri;
            re[i3] = qr - sr; im[i3] = qi - si;
        }
        __syncthreads();
    }
}

// ================= RPE hidden: u_t[j][pos] = relu(rms(h3)) =================
// thread = (pos in 0..63, feature-quarter), 128 blocks x 256 threads
__global__ __launch_bounds__(256) void rpe_hidden_kernel(
    const float* __restrict__ w_in, const float* __restrict__ b_in,
    const float* __restrict__ w_hid, const float* __restrict__ b_hid,
    float* __restrict__ u_t)
{
    __shared__ float4 wl[1024];      // W[j][0..63], row j = 16 float4
    __shared__ float ubuf[64][65];   // [pos][feat], stride 65 -> conflict-free
    __shared__ float sums[64][5];
    const int tid = threadIdx.x;
    const int p   = tid & 63;
    const int qr  = tid >> 6;        // quarter: features qr*16..qr*16+15
    const int pos = blockIdx.x * 64 + p;

    float v;
    if (pos == 0 || pos == N_SEQ) v = 1.0f;
    else if (pos < N_SEQ)         v = 1.0f / (float)(pos + 1);
    else                          v = -1.0f / (float)(2 * N_SEQ + 1 - pos);

    float h[16];
#pragma unroll
    for (int i = 0; i < 16; ++i) {
        int f = qr * 16 + i;
        h[i] = v * w_in[f] + b_in[f];
    }

    for (int L = 0; L < LAYERS; ++L) {
        const float4* wsrc = (const float4*)(w_hid + L * 4096);
#pragma unroll
        for (int i = 0; i < 4; ++i) wl[i * 256 + tid] = wsrc[i * 256 + tid];
        float s = 0.f;
#pragma unroll
        for (int i = 0; i < 16; ++i) s += h[i] * h[i];
        sums[p][qr] = s;
        __syncthreads();
        float tot = sums[p][0] + sums[p][1] + sums[p][2] + sums[p][3];
        float r = rsqrtf(tot * (1.f / 64.f) + 1e-8f);
#pragma unroll
        for (int i = 0; i < 16; ++i)
            ubuf[p][qr * 16 + i] = fmaxf(h[i] * r, 0.f);
        __syncthreads();
        float acc[16];
#pragma unroll
        for (int i = 0; i < 16; ++i) acc[i] = b_hid[L * 64 + qr * 16 + i];
#pragma unroll 4
        for (int j = 0; j < 64; ++j) {
            float uj = ubuf[p][j];
            float4 w0 = wl[j * 16 + qr * 4 + 0];
            float4 w1 = wl[j * 16 + qr * 4 + 1];
            float4 w2 = wl[j * 16 + qr * 4 + 2];
            float4 w3 = wl[j * 16 + qr * 4 + 3];
            acc[0]  = fmaf(uj, w0.x, acc[0]);  acc[1]  = fmaf(uj, w0.y, acc[1]);
            acc[2]  = fmaf(uj, w0.z, acc[2]);  acc[3]  = fmaf(uj, w0.w, acc[3]);
            acc[4]  = fmaf(uj, w1.x, acc[4]);  acc[5]  = fmaf(uj, w1.y, acc[5]);
            acc[6]  = fmaf(uj, w1.z, acc[6]);  acc[7]  = fmaf(uj, w1.w, acc[7]);
            acc[8]  = fmaf(uj, w2.x, acc[8]);  acc[9]  = fmaf(uj, w2.y, acc[9]);
            acc[10] = fmaf(uj, w2.z, acc[10]); acc[11] = fmaf(uj, w2.w, acc[11]);
            acc[12] = fmaf(uj, w3.x, acc[12]); acc[13] = fmaf(uj, w3.y, acc[13]);
            acc[14] = fmaf(uj, w3.z, acc[14]); acc[15] = fmaf(uj, w3.w, acc[15]);
        }
#pragma unroll
        for (int i = 0; i < 16; ++i) h[i] = acc[i];
        __syncthreads();   // wl/ubuf/sums reused next layer
    }
    float s = 0.f;
#pragma unroll
    for (int i = 0; i < 16; ++i) s += h[i] * h[i];
    sums[p][qr] = s;
    __syncthreads();
    float tot = sums[p][0] + sums[p][1] + sums[p][2] + sums[p][3];
    float r = rsqrtf(tot * (1.f / 64.f) + 1e-8f);
#pragma unroll
    for (int i = 0; i < 16; ++i)
        u_t[(size_t)(qr * 16 + i) * N_FFT + pos] = fmaxf(h[i] * r, 0.f);
}

// ================= RPE out GEMM: a_t[e][pos] = u^T W_out + b =================
// grid (32 pos-tiles, 8 e-chunks) x 256 threads; thread = position
__global__ __launch_bounds__(256) void rpe_out_kernel(
    const float* __restrict__ u_t, const float* __restrict__ w_out,
    const float* __restrict__ b_out, float* __restrict__ a_t)
{
    __shared__ float4 wl[1024];   // W_out[j][c*64..c*64+63]
    const int tid = threadIdx.x;
    const int c   = blockIdx.y;
    const int pos = blockIdx.x * 256 + tid;
    for (int i = tid; i < 1024; i += 256) {
        int j = i >> 4, q = i & 15;
        wl[i] = *(const float4*)(w_out + j * 512 + c * 64 + q * 4);
    }
    float acc[64];
#pragma unroll
    for (int f = 0; f < 64; ++f) acc[f] = b_out[c * 64 + f];
    __syncthreads();
#pragma unroll 2
    for (int j = 0; j < 64; ++j) {
        float uj = u_t[(size_t)j * N_FFT + pos];
#pragma unroll
        for (int q = 0; q < 16; ++q) {
            float4 w4 = wl[j * 16 + q];
            acc[q * 4 + 0] = fmaf(uj, w4.x, acc[q * 4 + 0]);
            acc[q * 4 + 1] = fmaf(uj, w4.y, acc[q * 4 + 1]);
            acc[q * 4 + 2] = fmaf(uj, w4.z, acc[q * 4 + 2]);
            acc[q * 4 + 3] = fmaf(uj, w4.w, acc[q * 4 + 3]);
        }
    }
#pragma unroll
    for (int f = 0; f < 64; ++f)
        a_t[(size_t)(c * 64 + f) * N_FFT + pos] = acc[f];
}

// ================= FFT of kernel a -> Af (digit-reversed order) =================
__global__ __launch_bounds__(FT) void fft_a_kernel(const float* __restrict__ a_t,
                                                   float2* __restrict__ Af)
{
    __shared__ float re[N_FFT];
    __shared__ float im[N_FFT];
    const int tid = threadIdx.x;
    const size_t row = blockIdx.x;
    const float* src = a_t + row * N_FFT;
    // fused first stage (m=8192), real input: im parts all zero
    const float wstep = -6.283185307179586f / 8192.f;
    for (int k = tid; k < 2048; k += FT) {
        float x0 = src[k], x1 = src[k + 2048], x2 = src[k + 4096], x3 = src[k + 6144];
        float ar = x0 + x2, br = x0 - x2;
        float cr = x1 + x3, e = x1 - x3;   // d = (0, -e)
        re[k] = ar + cr; im[k] = 0.f;
        float c1, s1; __sincosf(wstep * (float)k, &s1, &c1);
        float c2 = c1 * c1 - s1 * s1, s2 = 2.f * c1 * s1;
        float c3 = c2 * c1 - s2 * s1, s3 = c2 * s1 + s2 * c1;
        re[k + 2048] = br * c1 + e * s1;  im[k + 2048] = br * s1 - e * c1;   // t1=(br,-e)
        float t2r = ar - cr;
        re[k + 4096] = t2r * c2;          im[k + 4096] = t2r * s2;
        re[k + 6144] = br * c3 - e * s3;  im[k + 6144] = br * s3 + e * c3;   // t3=(br,+e)
    }
    __syncthreads();
    fft_dif_main(re, im, tid);
    float2* dst = Af + row * N_FFT;
    for (int i = tid; i < N_FFT; i += FT) dst[i] = make_float2(re[i], im[i]);
}

// ========== transpose x: (2,8,N,64) -> xt2[hd][n] = (x_b0, x_b1) ==========
__global__ __launch_bounds__(256) void transpose_x_kernel(const float* __restrict__ x,
                                                          float2* __restrict__ xt2)
{
    __shared__ float t0[64][65];
    __shared__ float t1[64][65];
    int h = blockIdx.x >> 6;
    int nb = blockIdx.x & 63;
    int lx = threadIdx.x & 63;
    int ly = threadIdx.x >> 6;
    const float* s0 = x + ((size_t)h * N_SEQ + nb * 64) * 64;
    const float* s1 = x + ((size_t)(8 + h) * N_SEQ + nb * 64) * 64;
    for (int r = ly; r < 64; r += 4) {
        t0[r][lx] = s0[r * 64 + lx];
        t1[r][lx] = s1[r * 64 + lx];
    }
    __syncthreads();
    for (int r = ly; r < 64; r += 4) {
        float2* dst = xt2 + (size_t)(h * 64 + r) * N_SEQ + nb * 64;
        dst[lx] = make_float2(t0[lx][r], t1[lx][r]);
    }
}

// ========== conv: per hd row, packed-complex FFT -> mult -> iFFT ==========
__global__ __launch_bounds__(FT) void conv_kernel(const float2* __restrict__ xt2,
                                                  const float2* __restrict__ Af,
                                                  float2* __restrict__ out_t2)
{
    __shared__ float re[N_FFT];
    __shared__ float im[N_FFT];
    const int tid = threadIdx.x;
    const int hd = blockIdx.x;
    const float2* src = xt2 + (size_t)hd * N_SEQ;
    // fused first forward stage (m=8192): x2=x3=0 (zero padding)
    {
        const float wstep = -6.283185307179586f / 8192.f;
        for (int k = tid; k < 2048; k += FT) {
            float2 z0 = src[k], z1 = src[k + 2048];
            float ar = z0.x, ai = z0.y;          // a = b = x0
            float cr = z1.x, ci = z1.y;          // c = x1
            float dr = z1.y, di = -z1.x;         // d = -i*x1
            re[k] = ar + cr; im[k] = ai + ci;
            float c1, s1; __sincosf(wstep * (float)k, &s1, &c1);
            float c2 = c1 * c1 - s1 * s1, s2 = 2.f * c1 * s1;
            float c3 = c2 * c1 - s2 * s1, s3 = c2 * s1 + s2 * c1;
            float t1r = ar + dr, t1i = ai + di;
            re[k + 2048] = t1r * c1 - t1i * s1; im[k + 2048] = t1r * s1 + t1i * c1;
            float t2r = ar - cr, t2i = ai - ci;
            re[k + 4096] = t2r * c2 - t2i * s2; im[k + 4096] = t2r * s2 + t2i * c2;
            float t3r = ar - dr, t3i = ai - di;
            re[k + 6144] = t3r * c3 - t3i * s3; im[k + 6144] = t3r * s3 + t3i * c3;
        }
    }
    __syncthreads();
    fft_dif_main(re, im, tid);
    const float2* af = Af + (size_t)hd * N_FFT;
    const float inv = 1.0f / (float)N_FFT;
    for (int i = tid; i < N_FFT; i += FT) {
        float2 a = af[i];
        float xr = re[i], xi = im[i];
        re[i] = (xr * a.x - xi * a.y) * inv;
        im[i] = (xr * a.y + xi * a.x) * inv;
    }
    __syncthreads();
    fft_inv_main(re, im, tid);
    // fused final inverse stage (m=8192): only outputs [0,4096) needed, store direct
    {
        const float wstep = 6.283185307179586f / 8192.f;
        float2* dst = out_t2 + (size_t)hd * N_SEQ;
        for (int k = tid; k < 2048; k += FT) {
            float c1, s1; __sincosf(wstep * (float)k, &s1, &c1);
            float c2 = c1 * c1 - s1 * s1, s2 = 2.f * c1 * s1;
            float c3 = c2 * c1 - s2 * s1, s3 = c2 * s1 + s2 * c1;
            float t0r = re[k],        t0i = im[k];
            float y1r = re[k + 2048], y1i = im[k + 2048];
            float y2r = re[k + 4096], y2i = im[k + 4096];
            float y3r = re[k + 6144], y3i = im[k + 6144];
            float t1r = y1r * c1 - y1i * s1, t1i = y1r * s1 + y1i * c1;
            float t2r = y2r * c2 - y2i * s2, t2i = y2r * s2 + y2i * c2;
            float t3r = y3r * c3 - y3i * s3, t3i = y3r * s3 + y3i * c3;
            float pr = t0r + t2r, pi = t0i + t2i;
            float qr = t0r - t2r, qi = t0i - t2i;
            float rr = t1r + t3r, ri = t1i + t3i;
            float sr = -(t1i - t3i), si = t1r - t3r;
            dst[k]        = make_float2(pr + rr, pi + ri);
            dst[k + 2048] = make_float2(qr + sr, qi + si);
        }
    }
}

// ========== transpose out: out_t2[hd][n] -> out (2,8,N,64) ==========
__global__ __launch_bounds__(256) void transpose_o_kernel(const float2* __restrict__ out_t2,
                                                          float* __restrict__ out)
{
    __shared__ float t0[64][65];
    __shared__ float t1[64][65];
    int h = blockIdx.x >> 6;
    int nb = blockIdx.x & 63;
    int lx = threadIdx.x & 63;
    int ly = threadIdx.x >> 6;
    for (int r = ly; r < 64; r += 4) {
        float2 v = out_t2[(size_t)(h * 64 + r) * N_SEQ + nb * 64 + lx];
        t0[r][lx] = v.x;
        t1[r][lx] = v.y;
    }
    __syncthreads();
    float* d0 = out + ((size_t)h * N_SEQ + nb * 64) * 64;
    float* d1 = out + ((size_t)(8 + h) * N_SEQ + nb * 64) * 64;
    for (int r = ly; r < 64; r += 4) {
        d0[r * 64 + lx] = t0[lx][r];
        d1[r * 64 + lx] = t1[lx][r];
    }
}

extern "C" void kernel_launch(void* const* d_in, const int* in_sizes, int n_in,
                              void* d_out, int out_size, void* d_ws, size_t ws_size,
                              hipStream_t stream)
{
    const float* x     = (const float*)d_in[0];
    const float* w_in  = (const float*)d_in[1];
    const float* b_in  = (const float*)d_in[2];
    const float* w_hid = (const float*)d_in[3];
    const float* b_hid = (const float*)d_in[4];
    const float* w_out = (const float*)d_in[5];
    const float* b_out = (const float*)d_in[6];
    float* out = (float*)d_out;

    char* ws = (char*)d_ws;
    float2* Af    = (float2*)ws;                               // 32 MB
    float2* xt2   = (float2*)(ws + (size_t)32 * 1024 * 1024);  // 16 MB
    float*  a_t   = (float*)(ws + (size_t)48 * 1024 * 1024);   // 16 MB
    float*  u_t   = (float*)xt2;      // 2 MB, consumed by rpe_out BEFORE transpose_x writes xt2
    float2* out_t2 = (float2*)a_t;    // consumed by fft_a BEFORE conv writes out_t2

    rpe_hidden_kernel<<<128, 256, 0, stream>>>(w_in, b_in, w_hid, b_hid, u_t);
    rpe_out_kernel<<<dim3(32, 8), 256, 0, stream>>>(u_t, w_out, b_out, a_t);
    fft_a_kernel<<<512, FT, 0, stream>>>(a_t, Af);
    transpose_x_kernel<<<512, 256, 0, stream>>>(x, xt2);
    conv_kernel<<<512, FT, 0, stream>>>(xt2, Af, out_t2);
    transpose_o_kernel<<<512, 256, 0, stream>>>(out_t2, out);
}

// Round 4
// 174.264 us; speedup vs baseline: 1.7977x; 1.0728x over previous
//
#include <hip/hip_runtime.h>

#define N_SEQ 4096
#define N_FFT 8192
#define LAYERS 3
#define FT 512                 // threads per FFT block
#define PIDX(i) ((i) + ((i) >> 5))   // +1 word per 32 -> all passes 2-way (free)

// =============== radix-16 pass: two DIF stages (M then M/4) in registers ===============
template<int M>
__device__ inline void pass16_fwd(float* re, float* im, int tid)
{
    const int Q = M >> 4;              // j' range
    const int j = tid & (Q - 1);
    const int G = tid / Q;
    const int base = G * M + j;
    float xr[4][4], xi[4][4];          // [a][b]
#pragma unroll
    for (int a = 0; a < 4; ++a)
#pragma unroll
        for (int b = 0; b < 4; ++b) {
            int idx = PIDX(base + a * (M >> 2) + b * Q);
            xr[a][b] = re[idx]; xi[a][b] = im[idx];
        }
    // stage M: butterfly over a, per-b twiddle j_m = b*Q + j
    const float w1 = -6.283185307179586f / (float)M;
#pragma unroll
    for (int b = 0; b < 4; ++b) {
        float ar = xr[0][b] + xr[2][b], ai = xi[0][b] + xi[2][b];
        float br = xr[0][b] - xr[2][b], bi = xi[0][b] - xi[2][b];
        float cr = xr[1][b] + xr[3][b], ci = xi[1][b] + xi[3][b];
        float dr = xi[1][b] - xi[3][b], di = -(xr[1][b] - xr[3][b]);
        float c1, s1; __sincosf(w1 * (float)(b * Q + j), &s1, &c1);
        float c2 = c1 * c1 - s1 * s1, s2 = 2.f * c1 * s1;
        float c3 = c2 * c1 - s2 * s1, s3 = c2 * s1 + s2 * c1;
        xr[0][b] = ar + cr;               xi[0][b] = ai + ci;
        float t1r = br + dr, t1i = bi + di;
        xr[1][b] = t1r * c1 - t1i * s1;   xi[1][b] = t1r * s1 + t1i * c1;
        float t2r = ar - cr, t2i = ai - ci;
        xr[2][b] = t2r * c2 - t2i * s2;   xi[2][b] = t2r * s2 + t2i * c2;
        float t3r = br - dr, t3i = bi - di;
        xr[3][b] = t3r * c3 - t3i * s3;   xi[3][b] = t3r * s3 + t3i * c3;
    }
    // stage M/4: butterfly over b, shared twiddle j
    {
        const float w4 = -6.283185307179586f / (float)(M >> 2);
        float c1, s1; __sincosf(w4 * (float)j, &s1, &c1);
        float c2 = c1 * c1 - s1 * s1, s2 = 2.f * c1 * s1;
        float c3 = c2 * c1 - s2 * s1, s3 = c2 * s1 + s2 * c1;
#pragma unroll
        for (int a = 0; a < 4; ++a) {
            float ar = xr[a][0] + xr[a][2], ai = xi[a][0] + xi[a][2];
            float br = xr[a][0] - xr[a][2], bi = xi[a][0] - xi[a][2];
            float cr = xr[a][1] + xr[a][3], ci = xi[a][1] + xi[a][3];
            float dr = xi[a][1] - xi[a][3], di = -(xr[a][1] - xr[a][3]);
            xr[a][0] = ar + cr;               xi[a][0] = ai + ci;
            float t1r = br + dr, t1i = bi + di;
            xr[a][1] = t1r * c1 - t1i * s1;   xi[a][1] = t1r * s1 + t1i * c1;
            float t2r = ar - cr, t2i = ai - ci;
            xr[a][2] = t2r * c2 - t2i * s2;   xi[a][2] = t2r * s2 + t2i * c2;
            float t3r = br - dr, t3i = bi - di;
            xr[a][3] = t3r * c3 - t3i * s3;   xi[a][3] = t3r * s3 + t3i * c3;
        }
    }
#pragma unroll
    for (int a = 0; a < 4; ++a)
#pragma unroll
        for (int b = 0; b < 4; ++b) {
            int idx = PIDX(base + a * (M >> 2) + b * Q);
            re[idx] = xr[a][b]; im[idx] = xi[a][b];
        }
}

// inverse: undo stage M/4 (over b, shared twiddle) then stage M (over a, per-b twiddle)
template<int M>
__device__ inline void pass16_inv(float* re, float* im, int tid)
{
    const int Q = M >> 4;
    const int j = tid & (Q - 1);
    const int G = tid / Q;
    const int base = G * M + j;
    float xr[4][4], xi[4][4];
#pragma unroll
    for (int a = 0; a < 4; ++a)
#pragma unroll
        for (int b = 0; b < 4; ++b) {
            int idx = PIDX(base + a * (M >> 2) + b * Q);
            xr[a][b] = re[idx]; xi[a][b] = im[idx];
        }
    {
        const float w4 = 6.283185307179586f / (float)(M >> 2);
        float c1, s1; __sincosf(w4 * (float)j, &s1, &c1);
        float c2 = c1 * c1 - s1 * s1, s2 = 2.f * c1 * s1;
        float c3 = c2 * c1 - s2 * s1, s3 = c2 * s1 + s2 * c1;
#pragma unroll
        for (int a = 0; a < 4; ++a) {
            float t0r = xr[a][0], t0i = xi[a][0];
            float t1r = xr[a][1] * c1 - xi[a][1] * s1, t1i = xr[a][1] * s1 + xi[a][1] * c1;
            float t2r = xr[a][2] * c2 - xi[a][2] * s2, t2i = xr[a][2] * s2 + xi[a][2] * c2;
            float t3r = xr[a][3] * c3 - xi[a][3] * s3, t3i = xr[a][3] * s3 + xi[a][3] * c3;
            float pr = t0r + t2r, pi = t0i + t2i;
            float qr = t0r - t2r, qi = t0i - t2i;
            float rr = t1r + t3r, ri = t1i + t3i;
            float sr = -(t1i - t3i), si = t1r - t3r;
            xr[a][0] = pr + rr; xi[a][0] = pi + ri;
            xr[a][1] = qr + sr; xi[a][1] = qi + si;
            xr[a][2] = pr - rr; xi[a][2] = pi - ri;
            xr[a][3] = qr - sr; xi[a][3] = qi - si;
        }
    }
    const float w1 = 6.283185307179586f / (float)M;
#pragma unroll
    for (int b = 0; b < 4; ++b) {
        float c1, s1; __sincosf(w1 * (float)(b * Q + j), &s1, &c1);
        float c2 = c1 * c1 - s1 * s1, s2 = 2.f * c1 * s1;
        float c3 = c2 * c1 - s2 * s1, s3 = c2 * s1 + s2 * c1;
        float t0r = xr[0][b], t0i = xi[0][b];
        float t1r = xr[1][b] * c1 - xi[1][b] * s1, t1i = xr[1][b] * s1 + xi[1][b] * c1;
        float t2r = xr[2][b] * c2 - xi[2][b] * s2, t2i = xr[2][b] * s2 + xi[2][b] * c2;
        float t3r = xr[3][b] * c3 - xi[3][b] * s3, t3i = xr[3][b] * s3 + xi[3][b] * c3;
        float pr = t0r + t2r, pi = t0i + t2i;
        float qr = t0r - t2r, qi = t0i - t2i;
        float rr = t1r + t3r, ri = t1i + t3i;
        float sr = -(t1i - t3i), si = t1r - t3r;
        xr[0][b] = pr + rr; xi[0][b] = pi + ri;
        xr[1][b] = qr + sr; xi[1][b] = qi + si;
        xr[2][b] = pr - rr; xi[2][b] = pi - ri;
        xr[3][b] = qr - sr; xi[3][b] = qi - si;
    }
#pragma unroll
    for (int a = 0; a < 4; ++a)
#pragma unroll
        for (int b = 0; b < 4; ++b) {
            int idx = PIDX(base + a * (M >> 2) + b * Q);
            re[idx] = xr[a][b]; im[idx] = xi[a][b];
        }
}

// ======= radix-8 tail (stage m=8 + r2), contiguous 8 points, constant twiddles =======
__device__ inline void fwd8(float* zr, float* zi, int o)
{
    const float R = 0.70710678118654752f;
    {   // j=0: o+0,2,4,6
        float ar = zr[o] + zr[o+4], ai = zi[o] + zi[o+4];
        float br = zr[o] - zr[o+4], bi = zi[o] - zi[o+4];
        float cr = zr[o+2] + zr[o+6], ci = zi[o+2] + zi[o+6];
        float dr = zi[o+2] - zi[o+6], di = -(zr[o+2] - zr[o+6]);
        zr[o]   = ar + cr; zi[o]   = ai + ci;
        zr[o+2] = br + dr; zi[o+2] = bi + di;
        zr[o+4] = ar - cr; zi[o+4] = ai - ci;
        zr[o+6] = br - dr; zi[o+6] = bi - di;
    }
    {   // j=1: o+1,3,5,7, twiddles W8^{1,2,3} = (R,-R),(0,-1),(-R,-R)
        float ar = zr[o+1] + zr[o+5], ai = zi[o+1] + zi[o+5];
        float br = zr[o+1] - zr[o+5], bi = zi[o+1] - zi[o+5];
        float cr = zr[o+3] + zr[o+7], ci = zi[o+3] + zi[o+7];
        float dr = zi[o+3] - zi[o+7], di = -(zr[o+3] - zr[o+7]);
        zr[o+1] = ar + cr; zi[o+1] = ai + ci;
        float t1r = br + dr, t1i = bi + di;
        zr[o+3] = R * (t1r + t1i); zi[o+3] = R * (t1i - t1r);
        float t2r = ar - cr, t2i = ai - ci;
        zr[o+5] = t2i;  zi[o+5] = -t2r;
        float t3r = br - dr, t3i = bi - di;
        zr[o+7] = R * (t3i - t3r); zi[o+7] = -R * (t3r + t3i);
    }
#pragma unroll
    for (int p = 0; p < 8; p += 2) {   // r2
        float ur = zr[o+p], ui = zi[o+p], vr = zr[o+p+1], vi = zi[o+p+1];
        zr[o+p]   = ur + vr; zi[o+p]   = ui + vi;
        zr[o+p+1] = ur - vr; zi[o+p+1] = ui - vi;
    }
}

__device__ inline void inv8(float* zr, float* zi, int o)
{
    const float R = 0.70710678118654752f;
#pragma unroll
    for (int p = 0; p < 8; p += 2) {   // undo r2
        float ur = zr[o+p], ui = zi[o+p], vr = zr[o+p+1], vi = zi[o+p+1];
        zr[o+p]   = ur + vr; zi[o+p]   = ui + vi;
        zr[o+p+1] = ur - vr; zi[o+p+1] = ui - vi;
    }
    {   // j=0
        float t0r = zr[o],   t0i = zi[o];
        float t1r = zr[o+2], t1i = zi[o+2];
        float t2r = zr[o+4], t2i = zi[o+4];
        float t3r = zr[o+6], t3i = zi[o+6];
        float pr = t0r + t2r, pi = t0i + t2i;
        float qr = t0r - t2r, qi = t0i - t2i;
        float rr = t1r + t3r, ri = t1i + t3i;
        float sr = -(t1i - t3i), si = t1r - t3r;
        zr[o]   = pr + rr; zi[o]   = pi + ri;
        zr[o+2] = qr + sr; zi[o+2] = qi + si;
        zr[o+4] = pr - rr; zi[o+4] = pi - ri;
        zr[o+6] = qr - sr; zi[o+6] = qi - si;
    }
    {   // j=1: twiddles conj -> (R,R),(0,1),(-R,R)
        float t0r = zr[o+1], t0i = zi[o+1];
        float yr = zr[o+3], yi = zi[o+3];
        float t1r = R * (yr - yi), t1i = R * (yr + yi);
        yr = zr[o+5]; yi = zi[o+5];
        float t2r = -yi, t2i = yr;
        yr = zr[o+7]; yi = zi[o+7];
        float t3r = -R * (yr + yi), t3i = R * (yr - yi);
        float pr = t0r + t2r, pi = t0i + t2i;
        float qr = t0r - t2r, qi = t0i - t2i;
        float rr = t1r + t3r, ri = t1i + t3i;
        float sr = -(t1i - t3i), si = t1r - t3r;
        zr[o+1] = pr + rr; zi[o+1] = pi + ri;
        zr[o+3] = qr + sr; zi[o+3] = qi + si;
        zr[o+5] = pr - rr; zi[o+5] = pi - ri;
        zr[o+7] = qr - sr; zi[o+7] = qi - si;
    }
}

// ================= RPE hidden: u_t[j][pos] = relu(rms(h3)) =================
__global__ __launch_bounds__(256) void rpe_hidden_kernel(
    const float* __restrict__ w_in, const float* __restrict__ b_in,
    const float* __restrict__ w_hid, const float* __restrict__ b_hid,
    float* __restrict__ u_t)
{
    __shared__ float4 wl[1024];
    __shared__ float ubuf[64][65];
    __shared__ float sums[64][5];
    const int tid = threadIdx.x;
    const int p   = tid & 63;
    const int qr  = tid >> 6;
    const int pos = blockIdx.x * 64 + p;

    float v;
    if (pos == 0 || pos == N_SEQ) v = 1.0f;
    else if (pos < N_SEQ)         v = 1.0f / (float)(pos + 1);
    else                          v = -1.0f / (float)(2 * N_SEQ + 1 - pos);

    float h[16];
#pragma unroll
    for (int i = 0; i < 16; ++i) {
        int f = qr * 16 + i;
        h[i] = v * w_in[f] + b_in[f];
    }
    for (int L = 0; L < LAYERS; ++L) {
        const float4* wsrc = (const float4*)(w_hid + L * 4096);
#pragma unroll
        for (int i = 0; i < 4; ++i) wl[i * 256 + tid] = wsrc[i * 256 + tid];
        float s = 0.f;
#pragma unroll
        for (int i = 0; i < 16; ++i) s += h[i] * h[i];
        sums[p][qr] = s;
        __syncthreads();
        float tot = sums[p][0] + sums[p][1] + sums[p][2] + sums[p][3];
        float r = rsqrtf(tot * (1.f / 64.f) + 1e-8f);
#pragma unroll
        for (int i = 0; i < 16; ++i)
            ubuf[p][qr * 16 + i] = fmaxf(h[i] * r, 0.f);
        __syncthreads();
        float acc[16];
#pragma unroll
        for (int i = 0; i < 16; ++i) acc[i] = b_hid[L * 64 + qr * 16 + i];
#pragma unroll 4
        for (int j = 0; j < 64; ++j) {
            float uj = ubuf[p][j];
            float4 w0 = wl[j * 16 + qr * 4 + 0];
            float4 w1 = wl[j * 16 + qr * 4 + 1];
            float4 w2 = wl[j * 16 + qr * 4 + 2];
            float4 w3 = wl[j * 16 + qr * 4 + 3];
            acc[0]  = fmaf(uj, w0.x, acc[0]);  acc[1]  = fmaf(uj, w0.y, acc[1]);
            acc[2]  = fmaf(uj, w0.z, acc[2]);  acc[3]  = fmaf(uj, w0.w, acc[3]);
            acc[4]  = fmaf(uj, w1.x, acc[4]);  acc[5]  = fmaf(uj, w1.y, acc[5]);
            acc[6]  = fmaf(uj, w1.z, acc[6]);  acc[7]  = fmaf(uj, w1.w, acc[7]);
            acc[8]  = fmaf(uj, w2.x, acc[8]);  acc[9]  = fmaf(uj, w2.y, acc[9]);
            acc[10] = fmaf(uj, w2.z, acc[10]); acc[11] = fmaf(uj, w2.w, acc[11]);
            acc[12] = fmaf(uj, w3.x, acc[12]); acc[13] = fmaf(uj, w3.y, acc[13]);
            acc[14] = fmaf(uj, w3.z, acc[14]); acc[15] = fmaf(uj, w3.w, acc[15]);
        }
#pragma unroll
        for (int i = 0; i < 16; ++i) h[i] = acc[i];
        __syncthreads();
    }
    float s = 0.f;
#pragma unroll
    for (int i = 0; i < 16; ++i) s += h[i] * h[i];
    sums[p][qr] = s;
    __syncthreads();
    float tot = sums[p][0] + sums[p][1] + sums[p][2] + sums[p][3];
    float r = rsqrtf(tot * (1.f / 64.f) + 1e-8f);
#pragma unroll
    for (int i = 0; i < 16; ++i)
        u_t[(size_t)(qr * 16 + i) * N_FFT + pos] = fmaxf(h[i] * r, 0.f);
}

// ================= RPE out GEMM =================
__global__ __launch_bounds__(256) void rpe_out_kernel(
    const float* __restrict__ u_t, const float* __restrict__ w_out,
    const float* __restrict__ b_out, float* __restrict__ a_t)
{
    __shared__ float4 wl[1024];
    const int tid = threadIdx.x;
    const int c   = blockIdx.y;
    const int pos = blockIdx.x * 256 + tid;
    for (int i = tid; i < 1024; i += 256) {
        int j = i >> 4, q = i & 15;
        wl[i] = *(const float4*)(w_out + j * 512 + c * 64 + q * 4);
    }
    float acc[64];
#pragma unroll
    for (int f = 0; f < 64; ++f) acc[f] = b_out[c * 64 + f];
    __syncthreads();
#pragma unroll 2
    for (int j = 0; j < 64; ++j) {
        float uj = u_t[(size_t)j * N_FFT + pos];
#pragma unroll
        for (int q = 0; q < 16; ++q) {
            float4 w4 = wl[j * 16 + q];
            acc[q * 4 + 0] = fmaf(uj, w4.x, acc[q * 4 + 0]);
            acc[q * 4 + 1] = fmaf(uj, w4.y, acc[q * 4 + 1]);
            acc[q * 4 + 2] = fmaf(uj, w4.z, acc[q * 4 + 2]);
            acc[q * 4 + 3] = fmaf(uj, w4.w, acc[q * 4 + 3]);
        }
    }
#pragma unroll
    for (int f = 0; f < 64; ++f)
        a_t[(size_t)(c * 64 + f) * N_FFT + pos] = acc[f];
}

// ================= FFT of kernel a -> Af (digit-reversed, includes 1/N) =================
__global__ __launch_bounds__(FT, 4) void fft_a_kernel(const float* __restrict__ a_t,
                                                      float2* __restrict__ Af)
{
    __shared__ float re[8448];
    __shared__ float im[8448];
    const int tid = threadIdx.x;
    const size_t row = blockIdx.x;
    const float* src = a_t + row * N_FFT;
    const float wstep = -6.283185307179586f / 8192.f;
#pragma unroll
    for (int k = tid; k < 2048; k += FT) {    // fused m=8192, real input
        float x0 = src[k], x1 = src[k + 2048], x2 = src[k + 4096], x3 = src[k + 6144];
        float ar = x0 + x2, br = x0 - x2;
        float cr = x1 + x3, e = x1 - x3;
        re[PIDX(k)] = ar + cr; im[PIDX(k)] = 0.f;
        float c1, s1; __sincosf(wstep * (float)k, &s1, &c1);
        float c2 = c1 * c1 - s1 * s1, s2 = 2.f * c1 * s1;
        float c3 = c2 * c1 - s2 * s1, s3 = c2 * s1 + s2 * c1;
        re[PIDX(k + 2048)] = br * c1 + e * s1;  im[PIDX(k + 2048)] = br * s1 - e * c1;
        float t2r = ar - cr;
        re[PIDX(k + 4096)] = t2r * c2;          im[PIDX(k + 4096)] = t2r * s2;
        re[PIDX(k + 6144)] = br * c3 - e * s3;  im[PIDX(k + 6144)] = br * s3 + e * c3;
    }
    __syncthreads();
    pass16_fwd<2048>(re, im, tid);
    __syncthreads();
    pass16_fwd<128>(re, im, tid);
    __syncthreads();
    // tail pass8 in registers -> store straight to global, fold 1/N
    float zr[16], zi[16];
    const int base = tid * 16;
#pragma unroll
    for (int c = 0; c < 16; ++c) { int idx = PIDX(base + c); zr[c] = re[idx]; zi[c] = im[idx]; }
    fwd8(zr, zi, 0); fwd8(zr, zi, 8);
    const float inv = 1.0f / (float)N_FFT;
    float4* dst4 = (float4*)(Af + row * N_FFT + base);
#pragma unroll
    for (int q = 0; q < 8; ++q)
        dst4[q] = make_float4(zr[2*q] * inv, zi[2*q] * inv, zr[2*q+1] * inv, zi[2*q+1] * inv);
}

// ========== transpose x: (2,8,N,64) -> xt2[hd][n] = (x_b0, x_b1) ==========
__global__ __launch_bounds__(256) void transpose_x_kernel(const float* __restrict__ x,
                                                          float2* __restrict__ xt2)
{
    __shared__ float t0[64][65];
    __shared__ float t1[64][65];
    int h = blockIdx.x >> 6;
    int nb = blockIdx.x & 63;
    int lx = threadIdx.x & 63;
    int ly = threadIdx.x >> 6;
    const float* s0 = x + ((size_t)h * N_SEQ + nb * 64) * 64;
    const float* s1 = x + ((size_t)(8 + h) * N_SEQ + nb * 64) * 64;
    for (int r = ly; r < 64; r += 4) {
        t0[r][lx] = s0[r * 64 + lx];
        t1[r][lx] = s1[r * 64 + lx];
    }
    __syncthreads();
    for (int r = ly; r < 64; r += 4) {
        float2* dst = xt2 + (size_t)(h * 64 + r) * N_SEQ + nb * 64;
        dst[lx] = make_float2(t0[lx][r], t1[lx][r]);
    }
}

// ========== conv: packed-complex FFT -> mult -> iFFT, 7 LDS passes ==========
__global__ __launch_bounds__(FT, 4) void conv_kernel(const float2* __restrict__ xt2,
                                                     const float2* __restrict__ Af,
                                                     float2* __restrict__ out_t2)
{
    __shared__ float re[8448];
    __shared__ float im[8448];
    const int tid = threadIdx.x;
    const int hd = blockIdx.x;
    const float2* src = xt2 + (size_t)hd * N_SEQ;
    {   // fused first forward stage (m=8192): x2=x3=0
        const float wstep = -6.283185307179586f / 8192.f;
#pragma unroll
        for (int k = tid; k < 2048; k += FT) {
            float2 z0 = src[k], z1 = src[k + 2048];
            float ar = z0.x, ai = z0.y;
            float cr = z1.x, ci = z1.y;
            float dr = z1.y, di = -z1.x;
            re[PIDX(k)] = ar + cr; im[PIDX(k)] = ai + ci;
            float c1, s1; __sincosf(wstep * (float)k, &s1, &c1);
            float c2 = c1 * c1 - s1 * s1, s2 = 2.f * c1 * s1;
            float c3 = c2 * c1 - s2 * s1, s3 = c2 * s1 + s2 * c1;
            float t1r = ar + dr, t1i = ai + di;
            re[PIDX(k + 2048)] = t1r * c1 - t1i * s1; im[PIDX(k + 2048)] = t1r * s1 + t1i * c1;
            float t2r = ar - cr, t2i = ai - ci;
            re[PIDX(k + 4096)] = t2r * c2 - t2i * s2; im[PIDX(k + 4096)] = t2r * s2 + t2i * c2;
            float t3r = ar - dr, t3i = ai - di;
            re[PIDX(k + 6144)] = t3r * c3 - t3i * s3; im[PIDX(k + 6144)] = t3r * s3 + t3i * c3;
        }
    }
    __syncthreads();
    pass16_fwd<2048>(re, im, tid);
    __syncthreads();
    pass16_fwd<128>(re, im, tid);
    __syncthreads();
    {   // fwd tail + Af multiply + inv head: all on contiguous 16 points, in registers
        float zr[16], zi[16];
        const int base = tid * 16;
#pragma unroll
        for (int c = 0; c < 16; ++c) { int idx = PIDX(base + c); zr[c] = re[idx]; zi[c] = im[idx]; }
        fwd8(zr, zi, 0); fwd8(zr, zi, 8);
        const float4* af4 = (const float4*)(Af + (size_t)hd * N_FFT + base);
#pragma unroll
        for (int q = 0; q < 8; ++q) {
            float4 a4 = af4[q];
            float xr = zr[2*q], xi_ = zi[2*q];
            zr[2*q]   = xr * a4.x - xi_ * a4.y;  zi[2*q]   = xr * a4.y + xi_ * a4.x;
            xr = zr[2*q+1]; xi_ = zi[2*q+1];
            zr[2*q+1] = xr * a4.z - xi_ * a4.w;  zi[2*q+1] = xr * a4.w + xi_ * a4.z;
        }
        inv8(zr, zi, 0); inv8(zr, zi, 8);
#pragma unroll
        for (int c = 0; c < 16; ++c) { int idx = PIDX(base + c); re[idx] = zr[c]; im[idx] = zi[c]; }
    }
    __syncthreads();
    pass16_inv<128>(re, im, tid);
    __syncthreads();
    pass16_inv<2048>(re, im, tid);
    __syncthreads();
    {   // fused final inverse stage (m=8192): store only [0,4096)
        const float wstep = 6.283185307179586f / 8192.f;
        float2* dst = out_t2 + (size_t)hd * N_SEQ;
#pragma unroll
        for (int k = tid; k < 2048; k += FT) {
            float c1, s1; __sincosf(wstep * (float)k, &s1, &c1);
            float c2 = c1 * c1 - s1 * s1, s2 = 2.f * c1 * s1;
            float c3 = c2 * c1 - s2 * s1, s3 = c2 * s1 + s2 * c1;
            float t0r = re[PIDX(k)],        t0i = im[PIDX(k)];
            float y1r = re[PIDX(k + 2048)], y1i = im[PIDX(k + 2048)];
            float y2r = re[PIDX(k + 4096)], y2i = im[PIDX(k + 4096)];
            float y3r = re[PIDX(k + 6144)], y3i = im[PIDX(k + 6144)];
            float t1r = y1r * c1 - y1i * s1, t1i = y1r * s1 + y1i * c1;
            float t2r = y2r * c2 - y2i * s2, t2i = y2r * s2 + y2i * c2;
            float t3r = y3r * c3 - y3i * s3, t3i = y3r * s3 + y3i * c3;
            float pr = t0r + t2r, pi = t0i + t2i;
            float qr = t0r - t2r, qi = t0i - t2i;
            float rr = t1r + t3r, ri = t1i + t3i;
            float sr = -(t1i - t3i), si = t1r - t3r;
            dst[k]        = make_float2(pr + rr, pi + ri);
            dst[k + 2048] = make_float2(qr + sr, qi + si);
        }
    }
}

// ========== transpose out ==========
__global__ __launch_bounds__(256) void transpose_o_kernel(const float2* __restrict__ out_t2,
                                                          float* __restrict__ out)
{
    __shared__ float t0[64][65];
    __shared__ float t1[64][65];
    int h = blockIdx.x >> 6;
    int nb = blockIdx.x & 63;
    int lx = threadIdx.x & 63;
    int ly = threadIdx.x >> 6;
    for (int r = ly; r < 64; r += 4) {
        float2 v = out_t2[(size_t)(h * 64 + r) * N_SEQ + nb * 64 + lx];
        t0[r][lx] = v.x;
        t1[r][lx] = v.y;
    }
    __syncthreads();
    float* d0 = out + ((size_t)h * N_SEQ + nb * 64) * 64;
    float* d1 = out + ((size_t)(8 + h) * N_SEQ + nb * 64) * 64;
    for (int r = ly; r < 64; r += 4) {
        d0[r * 64 + lx] = t0[lx][r];
        d1[r * 64 + lx] = t1[lx][r];
    }
}

extern "C" void kernel_launch(void* const* d_in, const int* in_sizes, int n_in,
                              void* d_out, int out_size, void* d_ws, size_t ws_size,
                              hipStream_t stream)
{
    const float* x     = (const float*)d_in[0];
    const float* w_in  = (const float*)d_in[1];
    const float* b_in  = (const float*)d_in[2];
    const float* w_hid = (const float*)d_in[3];
    const float* b_hid = (const float*)d_in[4];
    const float* w_out = (const float*)d_in[5];
    const float* b_out = (const float*)d_in[6];
    float* out = (float*)d_out;

    char* ws = (char*)d_ws;
    float2* Af    = (float2*)ws;                               // 32 MB
    float2* xt2   = (float2*)(ws + (size_t)32 * 1024 * 1024);  // 16 MB
    float*  a_t   = (float*)(ws + (size_t)48 * 1024 * 1024);   // 16 MB
    float*  u_t   = (float*)xt2;      // consumed by rpe_out BEFORE transpose_x writes xt2
    float2* out_t2 = (float2*)a_t;    // consumed by fft_a BEFORE conv writes out_t2

    rpe_hidden_kernel<<<128, 256, 0, stream>>>(w_in, b_in, w_hid, b_hid, u_t);
    rpe_out_kernel<<<dim3(32, 8), 256, 0, stream>>>(u_t, w_out, b_out, a_t);
    fft_a_kernel<<<512, FT, 0, stream>>>(a_t, Af);
    transpose_x_kernel<<<512, 256, 0, stream>>>(x, xt2);
    conv_kernel<<<512, FT, 0, stream>>>(xt2, Af, out_t2);
    transpose_o_kernel<<<512, 256, 0, stream>>>(out_t2, out);
}

// Round 5
// 169.710 us; speedup vs baseline: 1.8459x; 1.0268x over previous
//
#include <hip/hip_runtime.h>

#define N_SEQ 4096
#define N_FFT 8192
#define LAYERS 3
#define FT 512                 // threads per FFT block
#define PIDX(i) ((i) + ((i) >> 5))   // +1 word per 32 -> all passes 2-way (free)

// =============== radix-16 pass: two DIF stages (M then M/4) in registers ===============
// Twiddles: one sincos (W^j); W^{bQ+j} = W^j * K^b, K = e^{-2pi i/16} (Q = M/16);
// stage-M/4 twiddle W4^j = (W^j)^4 via two squarings.
template<int M>
__device__ inline void pass16_fwd(float* re, float* im, int tid)
{
    const int Q = M >> 4;
    const int j = tid & (Q - 1);
    const int G = tid / Q;
    const int base = G * M + j;
    const float KR[4] = {1.f, 0.9238795325f, 0.7071067812f, 0.3826834324f};
    const float KI[4] = {0.f, -0.3826834324f, -0.7071067812f, -0.9238795325f};
    float xr[4][4], xi[4][4];
#pragma unroll
    for (int a = 0; a < 4; ++a)
#pragma unroll
        for (int b = 0; b < 4; ++b) {
            int idx = PIDX(base + a * (M >> 2) + b * Q);
            xr[a][b] = re[idx]; xi[a][b] = im[idx];
        }
    float cj, sj;
    __sincosf(-6.283185307179586f / (float)M * (float)j, &sj, &cj);
    // stage M: butterfly over a, twiddle (cj,sj)*K^b
#pragma unroll
    for (int b = 0; b < 4; ++b) {
        float c1 = cj * KR[b] - sj * KI[b];
        float s1 = cj * KI[b] + sj * KR[b];
        float c2 = c1 * c1 - s1 * s1, s2 = 2.f * c1 * s1;
        float c3 = c2 * c1 - s2 * s1, s3 = c2 * s1 + s2 * c1;
        float ar = xr[0][b] + xr[2][b], ai = xi[0][b] + xi[2][b];
        float br = xr[0][b] - xr[2][b], bi = xi[0][b] - xi[2][b];
        float cr = xr[1][b] + xr[3][b], ci = xi[1][b] + xi[3][b];
        float dr = xi[1][b] - xi[3][b], di = -(xr[1][b] - xr[3][b]);
        xr[0][b] = ar + cr;               xi[0][b] = ai + ci;
        float t1r = br + dr, t1i = bi + di;
        xr[1][b] = t1r * c1 - t1i * s1;   xi[1][b] = t1r * s1 + t1i * c1;
        float t2r = ar - cr, t2i = ai - ci;
        xr[2][b] = t2r * c2 - t2i * s2;   xi[2][b] = t2r * s2 + t2i * c2;
        float t3r = br - dr, t3i = bi - di;
        xr[3][b] = t3r * c3 - t3i * s3;   xi[3][b] = t3r * s3 + t3i * c3;
    }
    // stage M/4: butterfly over b, twiddle (W^j)^4
    {
        float e1c = cj * cj - sj * sj, e1s = 2.f * cj * sj;      // W^{2j}
        float c1 = e1c * e1c - e1s * e1s, s1 = 2.f * e1c * e1s;  // W^{4j}
        float c2 = c1 * c1 - s1 * s1, s2 = 2.f * c1 * s1;
        float c3 = c2 * c1 - s2 * s1, s3 = c2 * s1 + s2 * c1;
#pragma unroll
        for (int a = 0; a < 4; ++a) {
            float ar = xr[a][0] + xr[a][2], ai = xi[a][0] + xi[a][2];
            float br = xr[a][0] - xr[a][2], bi = xi[a][0] - xi[a][2];
            float cr = xr[a][1] + xr[a][3], ci = xi[a][1] + xi[a][3];
            float dr = xi[a][1] - xi[a][3], di = -(xr[a][1] - xr[a][3]);
            xr[a][0] = ar + cr;               xi[a][0] = ai + ci;
            float t1r = br + dr, t1i = bi + di;
            xr[a][1] = t1r * c1 - t1i * s1;   xi[a][1] = t1r * s1 + t1i * c1;
            float t2r = ar - cr, t2i = ai - ci;
            xr[a][2] = t2r * c2 - t2i * s2;   xi[a][2] = t2r * s2 + t2i * c2;
            float t3r = br - dr, t3i = bi - di;
            xr[a][3] = t3r * c3 - t3i * s3;   xi[a][3] = t3r * s3 + t3i * c3;
        }
    }
#pragma unroll
    for (int a = 0; a < 4; ++a)
#pragma unroll
        for (int b = 0; b < 4; ++b) {
            int idx = PIDX(base + a * (M >> 2) + b * Q);
            re[idx] = xr[a][b]; im[idx] = xi[a][b];
        }
}

template<int M>
__device__ inline void pass16_inv(float* re, float* im, int tid)
{
    const int Q = M >> 4;
    const int j = tid & (Q - 1);
    const int G = tid / Q;
    const int base = G * M + j;
    const float KR[4] = {1.f, 0.9238795325f, 0.7071067812f, 0.3826834324f};
    const float KI[4] = {0.f, 0.3826834324f, 0.7071067812f, 0.9238795325f};   // conj
    float xr[4][4], xi[4][4];
#pragma unroll
    for (int a = 0; a < 4; ++a)
#pragma unroll
        for (int b = 0; b < 4; ++b) {
            int idx = PIDX(base + a * (M >> 2) + b * Q);
            xr[a][b] = re[idx]; xi[a][b] = im[idx];
        }
    float cj, sj;
    __sincosf(6.283185307179586f / (float)M * (float)j, &sj, &cj);
    // undo stage M/4 first: twiddle (W^j)^4 (e^{+i})
    {
        float e1c = cj * cj - sj * sj, e1s = 2.f * cj * sj;
        float c1 = e1c * e1c - e1s * e1s, s1 = 2.f * e1c * e1s;
        float c2 = c1 * c1 - s1 * s1, s2 = 2.f * c1 * s1;
        float c3 = c2 * c1 - s2 * s1, s3 = c2 * s1 + s2 * c1;
#pragma unroll
        for (int a = 0; a < 4; ++a) {
            float t0r = xr[a][0], t0i = xi[a][0];
            float t1r = xr[a][1] * c1 - xi[a][1] * s1, t1i = xr[a][1] * s1 + xi[a][1] * c1;
            float t2r = xr[a][2] * c2 - xi[a][2] * s2, t2i = xr[a][2] * s2 + xi[a][2] * c2;
            float t3r = xr[a][3] * c3 - xi[a][3] * s3, t3i = xr[a][3] * s3 + xi[a][3] * c3;
            float pr = t0r + t2r, pi = t0i + t2i;
            float qr = t0r - t2r, qi = t0i - t2i;
            float rr = t1r + t3r, ri = t1i + t3i;
            float sr = -(t1i - t3i), si = t1r - t3r;
            xr[a][0] = pr + rr; xi[a][0] = pi + ri;
            xr[a][1] = qr + sr; xi[a][1] = qi + si;
            xr[a][2] = pr - rr; xi[a][2] = pi - ri;
            xr[a][3] = qr - sr; xi[a][3] = qi - si;
        }
    }
    // undo stage M: per-b twiddle (cj,sj)*Kc^b
#pragma unroll
    for (int b = 0; b < 4; ++b) {
        float c1 = cj * KR[b] - sj * KI[b];
        float s1 = cj * KI[b] + sj * KR[b];
        float c2 = c1 * c1 - s1 * s1, s2 = 2.f * c1 * s1;
        float c3 = c2 * c1 - s2 * s1, s3 = c2 * s1 + s2 * c1;
        float t0r = xr[0][b], t0i = xi[0][b];
        float t1r = xr[1][b] * c1 - xi[1][b] * s1, t1i = xr[1][b] * s1 + xi[1][b] * c1;
        float t2r = xr[2][b] * c2 - xi[2][b] * s2, t2i = xr[2][b] * s2 + xi[2][b] * c2;
        float t3r = xr[3][b] * c3 - xi[3][b] * s3, t3i = xr[3][b] * s3 + xi[3][b] * c3;
        float pr = t0r + t2r, pi = t0i + t2i;
        float qr = t0r - t2r, qi = t0i - t2i;
        float rr = t1r + t3r, ri = t1i + t3i;
        float sr = -(t1i - t3i), si = t1r - t3r;
        xr[0][b] = pr + rr; xi[0][b] = pi + ri;
        xr[1][b] = qr + sr; xi[1][b] = qi + si;
        xr[2][b] = pr - rr; xi[2][b] = pi - ri;
        xr[3][b] = qr - sr; xi[3][b] = qi - si;
    }
#pragma unroll
    for (int a = 0; a < 4; ++a)
#pragma unroll
        for (int b = 0; b < 4; ++b) {
            int idx = PIDX(base + a * (M >> 2) + b * Q);
            re[idx] = xr[a][b]; im[idx] = xi[a][b];
        }
}

// ======= radix-8 tail (stage m=8 + r2), contiguous 8 points, constant twiddles =======
__device__ inline void fwd8(float* zr, float* zi, int o)
{
    const float R = 0.70710678118654752f;
    {
        float ar = zr[o] + zr[o+4], ai = zi[o] + zi[o+4];
        float br = zr[o] - zr[o+4], bi = zi[o] - zi[o+4];
        float cr = zr[o+2] + zr[o+6], ci = zi[o+2] + zi[o+6];
        float dr = zi[o+2] - zi[o+6], di = -(zr[o+2] - zr[o+6]);
        zr[o]   = ar + cr; zi[o]   = ai + ci;
        zr[o+2] = br + dr; zi[o+2] = bi + di;
        zr[o+4] = ar - cr; zi[o+4] = ai - ci;
        zr[o+6] = br - dr; zi[o+6] = bi - di;
    }
    {
        float ar = zr[o+1] + zr[o+5], ai = zi[o+1] + zi[o+5];
        float br = zr[o+1] - zr[o+5], bi = zi[o+1] - zi[o+5];
        float cr = zr[o+3] + zr[o+7], ci = zi[o+3] + zi[o+7];
        float dr = zi[o+3] - zi[o+7], di = -(zr[o+3] - zr[o+7]);
        zr[o+1] = ar + cr; zi[o+1] = ai + ci;
        float t1r = br + dr, t1i = bi + di;
        zr[o+3] = R * (t1r + t1i); zi[o+3] = R * (t1i - t1r);
        float t2r = ar - cr, t2i = ai - ci;
        zr[o+5] = t2i;  zi[o+5] = -t2r;
        float t3r = br - dr, t3i = bi - di;
        zr[o+7] = R * (t3i - t3r); zi[o+7] = -R * (t3r + t3i);
    }
#pragma unroll
    for (int p = 0; p < 8; p += 2) {
        float ur = zr[o+p], ui = zi[o+p], vr = zr[o+p+1], vi = zi[o+p+1];
        zr[o+p]   = ur + vr; zi[o+p]   = ui + vi;
        zr[o+p+1] = ur - vr; zi[o+p+1] = ui - vi;
    }
}

__device__ inline void inv8(float* zr, float* zi, int o)
{
    const float R = 0.70710678118654752f;
#pragma unroll
    for (int p = 0; p < 8; p += 2) {
        float ur = zr[o+p], ui = zi[o+p], vr = zr[o+p+1], vi = zi[o+p+1];
        zr[o+p]   = ur + vr; zi[o+p]   = ui + vi;
        zr[o+p+1] = ur - vr; zi[o+p+1] = ui - vi;
    }
    {
        float t0r = zr[o],   t0i = zi[o];
        float t1r = zr[o+2], t1i = zi[o+2];
        float t2r = zr[o+4], t2i = zi[o+4];
        float t3r = zr[o+6], t3i = zi[o+6];
        float pr = t0r + t2r, pi = t0i + t2i;
        float qr = t0r - t2r, qi = t0i - t2i;
        float rr = t1r + t3r, ri = t1i + t3i;
        float sr = -(t1i - t3i), si = t1r - t3r;
        zr[o]   = pr + rr; zi[o]   = pi + ri;
        zr[o+2] = qr + sr; zi[o+2] = qi + si;
        zr[o+4] = pr - rr; zi[o+4] = pi - ri;
        zr[o+6] = qr - sr; zi[o+6] = qi - si;
    }
    {
        float t0r = zr[o+1], t0i = zi[o+1];
        float yr = zr[o+3], yi = zi[o+3];
        float t1r = R * (yr - yi), t1i = R * (yr + yi);
        yr = zr[o+5]; yi = zi[o+5];
        float t2r = -yi, t2i = yr;
        yr = zr[o+7]; yi = zi[o+7];
        float t3r = -R * (yr + yi), t3i = R * (yr - yi);
        float pr = t0r + t2r, pi = t0i + t2i;
        float qr = t0r - t2r, qi = t0i - t2i;
        float rr = t1r + t3r, ri = t1i + t3i;
        float sr = -(t1i - t3i), si = t1r - t3r;
        zr[o+1] = pr + rr; zi[o+1] = pi + ri;
        zr[o+3] = qr + sr; zi[o+3] = qi + si;
        zr[o+5] = pr - rr; zi[o+5] = pi - ri;
        zr[o+7] = qr - sr; zi[o+7] = qi - si;
    }
}

// ============ prep: [blocks 0..255] fused RPE MLP+out GEMM -> a_t
//              [blocks 256..767] transpose x -> xt2 ============
__global__ __launch_bounds__(256) void prep_kernel(
    const float* __restrict__ x,
    const float* __restrict__ w_in, const float* __restrict__ b_in,
    const float* __restrict__ w_hid, const float* __restrict__ b_hid,
    const float* __restrict__ w_out, const float* __restrict__ b_out,
    float* __restrict__ a_t, float2* __restrict__ xt2)
{
    __shared__ __align__(16) char smem[33536];
    const int tid = threadIdx.x;

    if (blockIdx.x >= 256) {
        // ---- transpose x: (2,8,N,64) -> xt2[hd][n] = (x_b0, x_b1) ----
        float (*t0)[65] = (float (*)[65])smem;
        float (*t1)[65] = (float (*)[65])(smem + 16640);
        int bb = blockIdx.x - 256;
        int h = bb >> 6;
        int nb = bb & 63;
        int lx = tid & 63;
        int ly = tid >> 6;
        const float* s0 = x + ((size_t)h * N_SEQ + nb * 64) * 64;
        const float* s1 = x + ((size_t)(8 + h) * N_SEQ + nb * 64) * 64;
        for (int r = ly; r < 64; r += 4) {
            t0[r][lx] = s0[r * 64 + lx];
            t1[r][lx] = s1[r * 64 + lx];
        }
        __syncthreads();
        for (int r = ly; r < 64; r += 4) {
            float2* dst = xt2 + (size_t)(h * 64 + r) * N_SEQ + nb * 64;
            dst[lx] = make_float2(t0[lx][r], t1[lx][r]);
        }
        return;
    }

    // ---- RPE: 32 positions per block, thread = (p:32, oct:8) ----
    float4* wl       = (float4*)smem;                      // 16 KB
    float (*ubuf)[65] = (float (*)[65])(smem + 16384);     // 8320 B
    float (*sums)[9]  = (float (*)[9])(smem + 24704);      // 1152 B
    const int p   = tid & 31;
    const int oct = tid >> 5;
    const int pos = blockIdx.x * 32 + p;

    float v;
    if (pos == 0 || pos == N_SEQ) v = 1.0f;
    else if (pos < N_SEQ)         v = 1.0f / (float)(pos + 1);
    else                          v = -1.0f / (float)(2 * N_SEQ + 1 - pos);

    float h[8];
#pragma unroll
    for (int i = 0; i < 8; ++i) {
        int f = oct * 8 + i;
        h[i] = v * w_in[f] + b_in[f];
    }
    for (int L = 0; L < LAYERS; ++L) {
        const float4* wsrc = (const float4*)(w_hid + L * 4096);
#pragma unroll
        for (int i = 0; i < 4; ++i) wl[i * 256 + tid] = wsrc[i * 256 + tid];
        float s = 0.f;
#pragma unroll
        for (int i = 0; i < 8; ++i) s += h[i] * h[i];
        sums[p][oct] = s;
        __syncthreads();
        float tot = 0.f;
#pragma unroll
        for (int g = 0; g < 8; ++g) tot += sums[p][g];
        float r = rsqrtf(tot * (1.f / 64.f) + 1e-8f);
#pragma unroll
        for (int i = 0; i < 8; ++i)
            ubuf[p][oct * 8 + i] = fmaxf(h[i] * r, 0.f);
        __syncthreads();
        float acc[8];
#pragma unroll
        for (int i = 0; i < 8; ++i) acc[i] = b_hid[L * 64 + oct * 8 + i];
#pragma unroll 4
        for (int j = 0; j < 64; ++j) {
            float uj = ubuf[p][j];
            float4 w0 = wl[j * 16 + oct * 2];
            float4 w1 = wl[j * 16 + oct * 2 + 1];
            acc[0] = fmaf(uj, w0.x, acc[0]); acc[1] = fmaf(uj, w0.y, acc[1]);
            acc[2] = fmaf(uj, w0.z, acc[2]); acc[3] = fmaf(uj, w0.w, acc[3]);
            acc[4] = fmaf(uj, w1.x, acc[4]); acc[5] = fmaf(uj, w1.y, acc[5]);
            acc[6] = fmaf(uj, w1.z, acc[6]); acc[7] = fmaf(uj, w1.w, acc[7]);
        }
#pragma unroll
        for (int i = 0; i < 8; ++i) h[i] = acc[i];
        __syncthreads();
    }
    {   // final rms + relu -> ubuf
        float s = 0.f;
#pragma unroll
        for (int i = 0; i < 8; ++i) s += h[i] * h[i];
        sums[p][oct] = s;
        __syncthreads();
        float tot = 0.f;
#pragma unroll
        for (int g = 0; g < 8; ++g) tot += sums[p][g];
        float r = rsqrtf(tot * (1.f / 64.f) + 1e-8f);
#pragma unroll
        for (int i = 0; i < 8; ++i)
            ubuf[p][oct * 8 + i] = fmaxf(h[i] * r, 0.f);
        __syncthreads();
    }
    // out GEMM: 8 chunks of 64 output features
    for (int c = 0; c < 8; ++c) {
        float4 wreg[4];
#pragma unroll
        for (int cc = 0; cc < 4; ++cc) {
            int i4 = cc * 256 + tid;
            int j = i4 >> 4, q = i4 & 15;
            wreg[cc] = *(const float4*)(w_out + j * 512 + c * 64 + q * 4);
        }
        __syncthreads();   // prior chunk's wl reads done
#pragma unroll
        for (int cc = 0; cc < 4; ++cc) wl[cc * 256 + tid] = wreg[cc];
        __syncthreads();
        float acc[8];
#pragma unroll
        for (int i = 0; i < 8; ++i) acc[i] = b_out[c * 64 + oct * 8 + i];
#pragma unroll 4
        for (int j = 0; j < 64; ++j) {
            float uj = ubuf[p][j];
            float4 w0 = wl[j * 16 + oct * 2];
            float4 w1 = wl[j * 16 + oct * 2 + 1];
            acc[0] = fmaf(uj, w0.x, acc[0]); acc[1] = fmaf(uj, w0.y, acc[1]);
            acc[2] = fmaf(uj, w0.z, acc[2]); acc[3] = fmaf(uj, w0.w, acc[3]);
            acc[4] = fmaf(uj, w1.x, acc[4]); acc[5] = fmaf(uj, w1.y, acc[5]);
            acc[6] = fmaf(uj, w1.z, acc[6]); acc[7] = fmaf(uj, w1.w, acc[7]);
        }
#pragma unroll
        for (int i = 0; i < 8; ++i)
            a_t[(size_t)(c * 64 + oct * 8 + i) * N_FFT + pos] = acc[i];
    }
}

// ========== conv: A-FFT (spectrum kept in regs) + z-FFT + mult + iFFT ==========
__global__ __launch_bounds__(FT, 4) void conv_kernel(const float* __restrict__ a_t,
                                                     const float2* __restrict__ xt2,
                                                     float2* __restrict__ out_t2)
{
    __shared__ float re[8448];
    __shared__ float im[8448];
    const int tid = threadIdx.x;
    const int hd = blockIdx.x;
    const float JR = 0.9238795325f;        // e^{-2pi i/16}
    const float JI = -0.3826834324f;

    // ---- A forward: fused m=8192 stage (real input) ----
    {
        const float* src = a_t + (size_t)hd * N_FFT;
        float ck, sk;
        __sincosf(-6.283185307179586f / 8192.f * (float)tid, &sk, &ck);
#pragma unroll
        for (int pp = 0; pp < 4; ++pp) {
            int k = pp * FT + tid;
            float x0 = src[k], x1 = src[k + 2048], x2 = src[k + 4096], x3 = src[k + 6144];
            float ar = x0 + x2, br = x0 - x2;
            float cr = x1 + x3, e = x1 - x3;
            re[PIDX(k)] = ar + cr; im[PIDX(k)] = 0.f;
            float c1 = ck, s1 = sk;
            float c2 = c1 * c1 - s1 * s1, s2 = 2.f * c1 * s1;
            float c3 = c2 * c1 - s2 * s1, s3 = c2 * s1 + s2 * c1;
            re[PIDX(k + 2048)] = br * c1 + e * s1;  im[PIDX(k + 2048)] = br * s1 - e * c1;
            float t2r = ar - cr;
            re[PIDX(k + 4096)] = t2r * c2;          im[PIDX(k + 4096)] = t2r * s2;
            re[PIDX(k + 6144)] = br * c3 - e * s3;  im[PIDX(k + 6144)] = br * s3 + e * c3;
            float tc = ck * JR - sk * JI; sk = ck * JI + sk * JR; ck = tc;  // W^{k+512}
        }
    }
    __syncthreads();
    pass16_fwd<2048>(re, im, tid);
    __syncthreads();
    pass16_fwd<128>(re, im, tid);
    __syncthreads();
    // ---- A tail: spectrum (scaled by 1/N) stays in registers ----
    float afr[16], afi[16];
    {
        const int base = tid * 16;
        float zr[16], zi[16];
#pragma unroll
        for (int c = 0; c < 16; ++c) { int idx = PIDX(base + c); zr[c] = re[idx]; zi[c] = im[idx]; }
        fwd8(zr, zi, 0); fwd8(zr, zi, 8);
        const float inv = 1.0f / (float)N_FFT;
#pragma unroll
        for (int c = 0; c < 16; ++c) { afr[c] = zr[c] * inv; afi[c] = zi[c] * inv; }
    }
    __syncthreads();
    // ---- Z forward: fused m=8192 stage (packed complex, x2=x3=0) ----
    {
        const float2* src = xt2 + (size_t)hd * N_SEQ;
        float ck, sk;
        __sincosf(-6.283185307179586f / 8192.f * (float)tid, &sk, &ck);
#pragma unroll
        for (int pp = 0; pp < 4; ++pp) {
            int k = pp * FT + tid;
            float2 z0 = src[k], z1 = src[k + 2048];
            float ar = z0.x, ai = z0.y;
            float cr = z1.x, ci = z1.y;
            float dr = z1.y, di = -z1.x;
            re[PIDX(k)] = ar + cr; im[PIDX(k)] = ai + ci;
            float c1 = ck, s1 = sk;
            float c2 = c1 * c1 - s1 * s1, s2 = 2.f * c1 * s1;
            float c3 = c2 * c1 - s2 * s1, s3 = c2 * s1 + s2 * c1;
            float t1r = ar + dr, t1i = ai + di;
            re[PIDX(k + 2048)] = t1r * c1 - t1i * s1; im[PIDX(k + 2048)] = t1r * s1 + t1i * c1;
            float t2r = ar - cr, t2i = ai - ci;
            re[PIDX(k + 4096)] = t2r * c2 - t2i * s2; im[PIDX(k + 4096)] = t2r * s2 + t2i * c2;
            float t3r = ar - dr, t3i = ai - di;
            re[PIDX(k + 6144)] = t3r * c3 - t3i * s3; im[PIDX(k + 6144)] = t3r * s3 + t3i * c3;
            float tc = ck * JR - sk * JI; sk = ck * JI + sk * JR; ck = tc;
        }
    }
    __syncthreads();
    pass16_fwd<2048>(re, im, tid);
    __syncthreads();
    pass16_fwd<128>(re, im, tid);
    __syncthreads();
    {   // Z tail + pointwise (af in regs) + inverse head
        const int base = tid * 16;
        float zr[16], zi[16];
#pragma unroll
        for (int c = 0; c < 16; ++c) { int idx = PIDX(base + c); zr[c] = re[idx]; zi[c] = im[idx]; }
        fwd8(zr, zi, 0); fwd8(zr, zi, 8);
#pragma unroll
        for (int c = 0; c < 16; ++c) {
            float xr = zr[c], xi_ = zi[c];
            zr[c] = xr * afr[c] - xi_ * afi[c];
            zi[c] = xr * afi[c] + xi_ * afr[c];
        }
        inv8(zr, zi, 0); inv8(zr, zi, 8);
#pragma unroll
        for (int c = 0; c < 16; ++c) { int idx = PIDX(base + c); re[idx] = zr[c]; im[idx] = zi[c]; }
    }
    __syncthreads();
    pass16_inv<128>(re, im, tid);
    __syncthreads();
    pass16_inv<2048>(re, im, tid);
    __syncthreads();
    {   // fused final inverse stage (m=8192): store only [0,4096)
        float2* dst = out_t2 + (size_t)hd * N_SEQ;
        float ck, sk;
        __sincosf(6.283185307179586f / 8192.f * (float)tid, &sk, &ck);
        const float JcR = 0.9238795325f, JcI = 0.3826834324f;
#pragma unroll
        for (int pp = 0; pp < 4; ++pp) {
            int k = pp * FT + tid;
            float c1 = ck, s1 = sk;
            float c2 = c1 * c1 - s1 * s1, s2 = 2.f * c1 * s1;
            float c3 = c2 * c1 - s2 * s1, s3 = c2 * s1 + s2 * c1;
            float t0r = re[PIDX(k)],        t0i = im[PIDX(k)];
            float y1r = re[PIDX(k + 2048)], y1i = im[PIDX(k + 2048)];
            float y2r = re[PIDX(k + 4096)], y2i = im[PIDX(k + 4096)];
            float y3r = re[PIDX(k + 6144)], y3i = im[PIDX(k + 6144)];
            float t1r = y1r * c1 - y1i * s1, t1i = y1r * s1 + y1i * c1;
            float t2r = y2r * c2 - y2i * s2, t2i = y2r * s2 + y2i * c2;
            float t3r = y3r * c3 - y3i * s3, t3i = y3r * s3 + y3i * c3;
            float pr = t0r + t2r, pi = t0i + t2i;
            float qr = t0r - t2r, qi = t0i - t2i;
            float rr = t1r + t3r, ri = t1i + t3i;
            float sr = -(t1i - t3i), si = t1r - t3r;
            dst[k]        = make_float2(pr + rr, pi + ri);
            dst[k + 2048] = make_float2(qr + sr, qi + si);
            float tc = ck * JcR - sk * JcI; sk = ck * JcI + sk * JcR; ck = tc;
        }
    }
}

// ========== transpose out: out_t2[hd][n] -> out (2,8,N,64) ==========
__global__ __launch_bounds__(256) void transpose_o_kernel(const float2* __restrict__ out_t2,
                                                          float* __restrict__ out)
{
    __shared__ float t0[64][65];
    __shared__ float t1[64][65];
    int h = blockIdx.x >> 6;
    int nb = blockIdx.x & 63;
    int lx = threadIdx.x & 63;
    int ly = threadIdx.x >> 6;
    for (int r = ly; r < 64; r += 4) {
        float2 v = out_t2[(size_t)(h * 64 + r) * N_SEQ + nb * 64 + lx];
        t0[r][lx] = v.x;
        t1[r][lx] = v.y;
    }
    __syncthreads();
    float* d0 = out + ((size_t)h * N_SEQ + nb * 64) * 64;
    float* d1 = out + ((size_t)(8 + h) * N_SEQ + nb * 64) * 64;
    for (int r = ly; r < 64; r += 4) {
        d0[r * 64 + lx] = t0[lx][r];
        d1[r * 64 + lx] = t1[lx][r];
    }
}

extern "C" void kernel_launch(void* const* d_in, const int* in_sizes, int n_in,
                              void* d_out, int out_size, void* d_ws, size_t ws_size,
                              hipStream_t stream)
{
    const float* x     = (const float*)d_in[0];
    const float* w_in  = (const float*)d_in[1];
    const float* b_in  = (const float*)d_in[2];
    const float* w_hid = (const float*)d_in[3];
    const float* b_hid = (const float*)d_in[4];
    const float* w_out = (const float*)d_in[5];
    const float* b_out = (const float*)d_in[6];
    float* out = (float*)d_out;

    char* ws = (char*)d_ws;
    float2* xt2    = (float2*)ws;                               // 16 MB
    float*  a_t    = (float*)(ws + (size_t)16 * 1024 * 1024);   // 16 MB
    float2* out_t2 = (float2*)(ws + (size_t)32 * 1024 * 1024);  // 16 MB

    prep_kernel<<<768, 256, 0, stream>>>(x, w_in, b_in, w_hid, b_hid, w_out, b_out,
                                         a_t, xt2);
    conv_kernel<<<512, FT, 0, stream>>>(a_t, xt2, out_t2);
    transpose_o_kernel<<<512, 256, 0, stream>>>(out_t2, out);
}

// Round 6
// 151.119 us; speedup vs baseline: 2.0730x; 1.1230x over previous
//
#include <hip/hip_runtime.h>

#define N_SEQ 4096
#define N_FFT 8192
#define LAYERS 3
#define FT 512                 // threads per FFT block
#define PIDX(i) ((i) + ((i) >> 5))   // +1 word per 32 -> all passes 2-way (free)

// =============== radix-16 pass: two DIF stages (M then M/4) in registers ===============
template<int M>
__device__ inline void pass16_fwd(float* re, float* im, int tid)
{
    const int Q = M >> 4;
    const int j = tid & (Q - 1);
    const int G = tid / Q;
    const int base = G * M + j;
    const float KR[4] = {1.f, 0.9238795325f, 0.7071067812f, 0.3826834324f};
    const float KI[4] = {0.f, -0.3826834324f, -0.7071067812f, -0.9238795325f};
    float xr[4][4], xi[4][4];
#pragma unroll
    for (int a = 0; a < 4; ++a)
#pragma unroll
        for (int b = 0; b < 4; ++b) {
            int idx = PIDX(base + a * (M >> 2) + b * Q);
            xr[a][b] = re[idx]; xi[a][b] = im[idx];
        }
    float cj, sj;
    __sincosf(-6.283185307179586f / (float)M * (float)j, &sj, &cj);
#pragma unroll
    for (int b = 0; b < 4; ++b) {
        float c1 = cj * KR[b] - sj * KI[b];
        float s1 = cj * KI[b] + sj * KR[b];
        float c2 = c1 * c1 - s1 * s1, s2 = 2.f * c1 * s1;
        float c3 = c2 * c1 - s2 * s1, s3 = c2 * s1 + s2 * c1;
        float ar = xr[0][b] + xr[2][b], ai = xi[0][b] + xi[2][b];
        float br = xr[0][b] - xr[2][b], bi = xi[0][b] - xi[2][b];
        float cr = xr[1][b] + xr[3][b], ci = xi[1][b] + xi[3][b];
        float dr = xi[1][b] - xi[3][b], di = -(xr[1][b] - xr[3][b]);
        xr[0][b] = ar + cr;               xi[0][b] = ai + ci;
        float t1r = br + dr, t1i = bi + di;
        xr[1][b] = t1r * c1 - t1i * s1;   xi[1][b] = t1r * s1 + t1i * c1;
        float t2r = ar - cr, t2i = ai - ci;
        xr[2][b] = t2r * c2 - t2i * s2;   xi[2][b] = t2r * s2 + t2i * c2;
        float t3r = br - dr, t3i = bi - di;
        xr[3][b] = t3r * c3 - t3i * s3;   xi[3][b] = t3r * s3 + t3i * c3;
    }
    {
        float e1c = cj * cj - sj * sj, e1s = 2.f * cj * sj;      // W^{2j}
        float c1 = e1c * e1c - e1s * e1s, s1 = 2.f * e1c * e1s;  // W^{4j}
        float c2 = c1 * c1 - s1 * s1, s2 = 2.f * c1 * s1;
        float c3 = c2 * c1 - s2 * s1, s3 = c2 * s1 + s2 * c1;
#pragma unroll
        for (int a = 0; a < 4; ++a) {
            float ar = xr[a][0] + xr[a][2], ai = xi[a][0] + xi[a][2];
            float br = xr[a][0] - xr[a][2], bi = xi[a][0] - xi[a][2];
            float cr = xr[a][1] + xr[a][3], ci = xi[a][1] + xi[a][3];
            float dr = xi[a][1] - xi[a][3], di = -(xr[a][1] - xr[a][3]);
            xr[a][0] = ar + cr;               xi[a][0] = ai + ci;
            float t1r = br + dr, t1i = bi + di;
            xr[a][1] = t1r * c1 - t1i * s1;   xi[a][1] = t1r * s1 + t1i * c1;
            float t2r = ar - cr, t2i = ai - ci;
            xr[a][2] = t2r * c2 - t2i * s2;   xi[a][2] = t2r * s2 + t2i * c2;
            float t3r = br - dr, t3i = bi - di;
            xr[a][3] = t3r * c3 - t3i * s3;   xi[a][3] = t3r * s3 + t3i * c3;
        }
    }
#pragma unroll
    for (int a = 0; a < 4; ++a)
#pragma unroll
        for (int b = 0; b < 4; ++b) {
            int idx = PIDX(base + a * (M >> 2) + b * Q);
            re[idx] = xr[a][b]; im[idx] = xi[a][b];
        }
}

template<int M>
__device__ inline void pass16_inv(float* re, float* im, int tid)
{
    const int Q = M >> 4;
    const int j = tid & (Q - 1);
    const int G = tid / Q;
    const int base = G * M + j;
    const float KR[4] = {1.f, 0.9238795325f, 0.7071067812f, 0.3826834324f};
    const float KI[4] = {0.f, 0.3826834324f, 0.7071067812f, 0.9238795325f};   // conj
    float xr[4][4], xi[4][4];
#pragma unroll
    for (int a = 0; a < 4; ++a)
#pragma unroll
        for (int b = 0; b < 4; ++b) {
            int idx = PIDX(base + a * (M >> 2) + b * Q);
            xr[a][b] = re[idx]; xi[a][b] = im[idx];
        }
    float cj, sj;
    __sincosf(6.283185307179586f / (float)M * (float)j, &sj, &cj);
    {
        float e1c = cj * cj - sj * sj, e1s = 2.f * cj * sj;
        float c1 = e1c * e1c - e1s * e1s, s1 = 2.f * e1c * e1s;
        float c2 = c1 * c1 - s1 * s1, s2 = 2.f * c1 * s1;
        float c3 = c2 * c1 - s2 * s1, s3 = c2 * s1 + s2 * c1;
#pragma unroll
        for (int a = 0; a < 4; ++a) {
            float t0r = xr[a][0], t0i = xi[a][0];
            float t1r = xr[a][1] * c1 - xi[a][1] * s1, t1i = xr[a][1] * s1 + xi[a][1] * c1;
            float t2r = xr[a][2] * c2 - xi[a][2] * s2, t2i = xr[a][2] * s2 + xi[a][2] * c2;
            float t3r = xr[a][3] * c3 - xi[a][3] * s3, t3i = xr[a][3] * s3 + xi[a][3] * c3;
            float pr = t0r + t2r, pi = t0i + t2i;
            float qr = t0r - t2r, qi = t0i - t2i;
            float rr = t1r + t3r, ri = t1i + t3i;
            float sr = -(t1i - t3i), si = t1r - t3r;
            xr[a][0] = pr + rr; xi[a][0] = pi + ri;
            xr[a][1] = qr + sr; xi[a][1] = qi + si;
            xr[a][2] = pr - rr; xi[a][2] = pi - ri;
            xr[a][3] = qr - sr; xi[a][3] = qi - si;
        }
    }
#pragma unroll
    for (int b = 0; b < 4; ++b) {
        float c1 = cj * KR[b] - sj * KI[b];
        float s1 = cj * KI[b] + sj * KR[b];
        float c2 = c1 * c1 - s1 * s1, s2 = 2.f * c1 * s1;
        float c3 = c2 * c1 - s2 * s1, s3 = c2 * s1 + s2 * c1;
        float t0r = xr[0][b], t0i = xi[0][b];
        float t1r = xr[1][b] * c1 - xi[1][b] * s1, t1i = xr[1][b] * s1 + xi[1][b] * c1;
        float t2r = xr[2][b] * c2 - xi[2][b] * s2, t2i = xr[2][b] * s2 + xi[2][b] * c2;
        float t3r = xr[3][b] * c3 - xi[3][b] * s3, t3i = xr[3][b] * s3 + xi[3][b] * c3;
        float pr = t0r + t2r, pi = t0i + t2i;
        float qr = t0r - t2r, qi = t0i - t2i;
        float rr = t1r + t3r, ri = t1i + t3i;
        float sr = -(t1i - t3i), si = t1r - t3r;
        xr[0][b] = pr + rr; xi[0][b] = pi + ri;
        xr[1][b] = qr + sr; xi[1][b] = qi + si;
        xr[2][b] = pr - rr; xi[2][b] = pi - ri;
        xr[3][b] = qr - sr; xi[3][b] = qi - si;
    }
#pragma unroll
    for (int a = 0; a < 4; ++a)
#pragma unroll
        for (int b = 0; b < 4; ++b) {
            int idx = PIDX(base + a * (M >> 2) + b * Q);
            re[idx] = xr[a][b]; im[idx] = xi[a][b];
        }
}

// ======= radix-8 tail (stage m=8 + r2), contiguous 8 points, constant twiddles =======
__device__ inline void fwd8(float* zr, float* zi, int o)
{
    const float R = 0.70710678118654752f;
    {
        float ar = zr[o] + zr[o+4], ai = zi[o] + zi[o+4];
        float br = zr[o] - zr[o+4], bi = zi[o] - zi[o+4];
        float cr = zr[o+2] + zr[o+6], ci = zi[o+2] + zi[o+6];
        float dr = zi[o+2] - zi[o+6], di = -(zr[o+2] - zr[o+6]);
        zr[o]   = ar + cr; zi[o]   = ai + ci;
        zr[o+2] = br + dr; zi[o+2] = bi + di;
        zr[o+4] = ar - cr; zi[o+4] = ai - ci;
        zr[o+6] = br - dr; zi[o+6] = bi - di;
    }
    {
        float ar = zr[o+1] + zr[o+5], ai = zi[o+1] + zi[o+5];
        float br = zr[o+1] - zr[o+5], bi = zi[o+1] - zi[o+5];
        float cr = zr[o+3] + zr[o+7], ci = zi[o+3] + zi[o+7];
        float dr = zi[o+3] - zi[o+7], di = -(zr[o+3] - zr[o+7]);
        zr[o+1] = ar + cr; zi[o+1] = ai + ci;
        float t1r = br + dr, t1i = bi + di;
        zr[o+3] = R * (t1r + t1i); zi[o+3] = R * (t1i - t1r);
        float t2r = ar - cr, t2i = ai - ci;
        zr[o+5] = t2i;  zi[o+5] = -t2r;
        float t3r = br - dr, t3i = bi - di;
        zr[o+7] = R * (t3i - t3r); zi[o+7] = -R * (t3r + t3i);
    }
#pragma unroll
    for (int p = 0; p < 8; p += 2) {
        float ur = zr[o+p], ui = zi[o+p], vr = zr[o+p+1], vi = zi[o+p+1];
        zr[o+p]   = ur + vr; zi[o+p]   = ui + vi;
        zr[o+p+1] = ur - vr; zi[o+p+1] = ui - vi;
    }
}

__device__ inline void inv8(float* zr, float* zi, int o)
{
    const float R = 0.70710678118654752f;
#pragma unroll
    for (int p = 0; p < 8; p += 2) {
        float ur = zr[o+p], ui = zi[o+p], vr = zr[o+p+1], vi = zi[o+p+1];
        zr[o+p]   = ur + vr; zi[o+p]   = ui + vi;
        zr[o+p+1] = ur - vr; zi[o+p+1] = ui - vi;
    }
    {
        float t0r = zr[o],   t0i = zi[o];
        float t1r = zr[o+2], t1i = zi[o+2];
        float t2r = zr[o+4], t2i = zi[o+4];
        float t3r = zr[o+6], t3i = zi[o+6];
        float pr = t0r + t2r, pi = t0i + t2i;
        float qr = t0r - t2r, qi = t0i - t2i;
        float rr = t1r + t3r, ri = t1i + t3i;
        float sr = -(t1i - t3i), si = t1r - t3r;
        zr[o]   = pr + rr; zi[o]   = pi + ri;
        zr[o+2] = qr + sr; zi[o+2] = qi + si;
        zr[o+4] = pr - rr; zi[o+4] = pi - ri;
        zr[o+6] = qr - sr; zi[o+6] = qi - si;
    }
    {
        float t0r = zr[o+1], t0i = zi[o+1];
        float yr = zr[o+3], yi = zi[o+3];
        float t1r = R * (yr - yi), t1i = R * (yr + yi);
        yr = zr[o+5]; yi = zi[o+5];
        float t2r = -yi, t2i = yr;
        yr = zr[o+7]; yi = zi[o+7];
        float t3r = -R * (yr + yi), t3i = R * (yr - yi);
        float pr = t0r + t2r, pi = t0i + t2i;
        float qr = t0r - t2r, qi = t0i - t2i;
        float rr = t1r + t3r, ri = t1i + t3i;
        float sr = -(t1i - t3i), si = t1r - t3r;
        zr[o+1] = pr + rr; zi[o+1] = pi + ri;
        zr[o+3] = qr + sr; zi[o+3] = qi + si;
        zr[o+5] = pr - rr; zi[o+5] = pi - ri;
        zr[o+7] = qr - sr; zi[o+7] = qi - si;
    }
}

// ============ prep: [blocks 0..127] fused RPE MLP+out GEMM -> a_t (64 pos/block)
//              [blocks 128..639] transpose x -> xt2 (1 tile/block, 512 thr) ============
__global__ __launch_bounds__(512) void prep_kernel(
    const float* __restrict__ x,
    const float* __restrict__ w_in, const float* __restrict__ b_in,
    const float* __restrict__ w_hid, const float* __restrict__ b_hid,
    const float* __restrict__ w_out, const float* __restrict__ b_out,
    float* __restrict__ a_t, float2* __restrict__ xt2)
{
    __shared__ __align__(16) char smem[35328];
    const int tid = threadIdx.x;

    if (blockIdx.x >= 128) {
        // ---- transpose x: (2,8,N,64) -> xt2[hd][n] = (x_b0, x_b1) ----
        float (*t0)[65] = (float (*)[65])smem;
        float (*t1)[65] = (float (*)[65])(smem + 16640);
        int bb = blockIdx.x - 128;
        int h = bb >> 6;
        int nb = bb & 63;
        int lx = tid & 63;
        int ly = tid >> 6;          // 0..7
        const float* s0 = x + ((size_t)h * N_SEQ + nb * 64) * 64;
        const float* s1 = x + ((size_t)(8 + h) * N_SEQ + nb * 64) * 64;
        for (int r = ly; r < 64; r += 8) {
            t0[r][lx] = s0[r * 64 + lx];
            t1[r][lx] = s1[r * 64 + lx];
        }
        __syncthreads();
        for (int r = ly; r < 64; r += 8) {
            float2* dst = xt2 + (size_t)(h * 64 + r) * N_SEQ + nb * 64;
            dst[lx] = make_float2(t0[lx][r], t1[lx][r]);
        }
        return;
    }

    // ---- RPE: 64 positions/block, thread = (p:64, oct:8) ----
    float4* wl        = (float4*)smem;                     // 16 KB
    float (*ubuf)[65] = (float (*)[65])(smem + 16384);     // 16640 B
    float (*sums)[9]  = (float (*)[9])(smem + 33024);      // 2304 B
    const int p   = tid & 63;
    const int oct = tid >> 6;
    const int pos = blockIdx.x * 64 + p;

    float v;
    if (pos == 0 || pos == N_SEQ) v = 1.0f;
    else if (pos < N_SEQ)         v = 1.0f / (float)(pos + 1);
    else                          v = -1.0f / (float)(2 * N_SEQ + 1 - pos);

    float h[8];
#pragma unroll
    for (int i = 0; i < 8; ++i) {
        int f = oct * 8 + i;
        h[i] = v * w_in[f] + b_in[f];
    }
    for (int L = 0; L < LAYERS; ++L) {
        const float4* wsrc = (const float4*)(w_hid + L * 4096);
        wl[tid] = wsrc[tid];
        wl[tid + 512] = wsrc[tid + 512];
        float s = 0.f;
#pragma unroll
        for (int i = 0; i < 8; ++i) s += h[i] * h[i];
        sums[p][oct] = s;
        __syncthreads();
        float tot = 0.f;
#pragma unroll
        for (int g = 0; g < 8; ++g) tot += sums[p][g];
        float r = rsqrtf(tot * (1.f / 64.f) + 1e-8f);
#pragma unroll
        for (int i = 0; i < 8; ++i)
            ubuf[p][oct * 8 + i] = fmaxf(h[i] * r, 0.f);
        __syncthreads();
        float acc[8];
#pragma unroll
        for (int i = 0; i < 8; ++i) acc[i] = b_hid[L * 64 + oct * 8 + i];
#pragma unroll 4
        for (int j = 0; j < 64; ++j) {
            float uj = ubuf[p][j];
            float4 w0 = wl[j * 16 + oct * 2];
            float4 w1 = wl[j * 16 + oct * 2 + 1];
            acc[0] = fmaf(uj, w0.x, acc[0]); acc[1] = fmaf(uj, w0.y, acc[1]);
            acc[2] = fmaf(uj, w0.z, acc[2]); acc[3] = fmaf(uj, w0.w, acc[3]);
            acc[4] = fmaf(uj, w1.x, acc[4]); acc[5] = fmaf(uj, w1.y, acc[5]);
            acc[6] = fmaf(uj, w1.z, acc[6]); acc[7] = fmaf(uj, w1.w, acc[7]);
        }
#pragma unroll
        for (int i = 0; i < 8; ++i) h[i] = acc[i];
        __syncthreads();
    }
    {
        float s = 0.f;
#pragma unroll
        for (int i = 0; i < 8; ++i) s += h[i] * h[i];
        sums[p][oct] = s;
        __syncthreads();
        float tot = 0.f;
#pragma unroll
        for (int g = 0; g < 8; ++g) tot += sums[p][g];
        float r = rsqrtf(tot * (1.f / 64.f) + 1e-8f);
#pragma unroll
        for (int i = 0; i < 8; ++i)
            ubuf[p][oct * 8 + i] = fmaxf(h[i] * r, 0.f);
        __syncthreads();
    }
    for (int c = 0; c < 8; ++c) {
        float4 wreg0, wreg1;
        {
            int i4 = tid;
            wreg0 = *(const float4*)(w_out + (i4 >> 4) * 512 + c * 64 + (i4 & 15) * 4);
            i4 = tid + 512;
            wreg1 = *(const float4*)(w_out + (i4 >> 4) * 512 + c * 64 + (i4 & 15) * 4);
        }
        __syncthreads();   // prior chunk's wl reads done
        wl[tid] = wreg0;
        wl[tid + 512] = wreg1;
        __syncthreads();
        float acc[8];
#pragma unroll
        for (int i = 0; i < 8; ++i) acc[i] = b_out[c * 64 + oct * 8 + i];
#pragma unroll 4
        for (int j = 0; j < 64; ++j) {
            float uj = ubuf[p][j];
            float4 w0 = wl[j * 16 + oct * 2];
            float4 w1 = wl[j * 16 + oct * 2 + 1];
            acc[0] = fmaf(uj, w0.x, acc[0]); acc[1] = fmaf(uj, w0.y, acc[1]);
            acc[2] = fmaf(uj, w0.z, acc[2]); acc[3] = fmaf(uj, w0.w, acc[3]);
            acc[4] = fmaf(uj, w1.x, acc[4]); acc[5] = fmaf(uj, w1.y, acc[5]);
            acc[6] = fmaf(uj, w1.z, acc[6]); acc[7] = fmaf(uj, w1.w, acc[7]);
        }
#pragma unroll
        for (int i = 0; i < 8; ++i)
            a_t[(size_t)(c * 64 + oct * 8 + i) * N_FFT + pos] = acc[i];
    }
}

// ========== conv: A-FFT (spectrum kept in regs) + z-FFT + mult + iFFT ==========
__global__ __launch_bounds__(FT, 2) void conv_kernel(const float* __restrict__ a_t,
                                                     const float2* __restrict__ xt2,
                                                     float2* __restrict__ out_t2)
{
    __shared__ float re[8448];
    __shared__ float im[8448];
    const int tid = threadIdx.x;
    const int hd = blockIdx.x;
    const float JR = 0.9238795325f;        // e^{-2pi i/16}
    const float JI = -0.3826834324f;

    // ---- A forward: fused m=8192 stage (real input) ----
    {
        const float* src = a_t + (size_t)hd * N_FFT;
        float ck, sk;
        __sincosf(-6.283185307179586f / 8192.f * (float)tid, &sk, &ck);
#pragma unroll
        for (int pp = 0; pp < 4; ++pp) {
            int k = pp * FT + tid;
            float x0 = src[k], x1 = src[k + 2048], x2 = src[k + 4096], x3 = src[k + 6144];
            float ar = x0 + x2, br = x0 - x2;
            float cr = x1 + x3, e = x1 - x3;
            re[PIDX(k)] = ar + cr; im[PIDX(k)] = 0.f;
            float c1 = ck, s1 = sk;
            float c2 = c1 * c1 - s1 * s1, s2 = 2.f * c1 * s1;
            float c3 = c2 * c1 - s2 * s1, s3 = c2 * s1 + s2 * c1;
            re[PIDX(k + 2048)] = br * c1 + e * s1;  im[PIDX(k + 2048)] = br * s1 - e * c1;
            float t2r = ar - cr;
            re[PIDX(k + 4096)] = t2r * c2;          im[PIDX(k + 4096)] = t2r * s2;
            re[PIDX(k + 6144)] = br * c3 - e * s3;  im[PIDX(k + 6144)] = br * s3 + e * c3;
            float tc = ck * JR - sk * JI; sk = ck * JI + sk * JR; ck = tc;  // W^{k+512}
        }
    }
    __syncthreads();
    pass16_fwd<2048>(re, im, tid);
    __syncthreads();
    pass16_fwd<128>(re, im, tid);
    __syncthreads();
    // ---- A tail: unscaled spectrum stays in registers (1/N folded in later) ----
    float afr[16], afi[16];
    {
        const int base = tid * 16;
#pragma unroll
        for (int c = 0; c < 16; ++c) { int idx = PIDX(base + c); afr[c] = re[idx]; afi[c] = im[idx]; }
        fwd8(afr, afi, 0); fwd8(afr, afi, 8);
    }
    __syncthreads();
    // ---- Z forward: fused m=8192 stage (packed complex, x2=x3=0) ----
    {
        const float2* src = xt2 + (size_t)hd * N_SEQ;
        float ck, sk;
        __sincosf(-6.283185307179586f / 8192.f * (float)tid, &sk, &ck);
#pragma unroll
        for (int pp = 0; pp < 4; ++pp) {
            int k = pp * FT + tid;
            float2 z0 = src[k], z1 = src[k + 2048];
            float ar = z0.x, ai = z0.y;
            float cr = z1.x, ci = z1.y;
            float dr = z1.y, di = -z1.x;
            re[PIDX(k)] = ar + cr; im[PIDX(k)] = ai + ci;
            float c1 = ck, s1 = sk;
            float c2 = c1 * c1 - s1 * s1, s2 = 2.f * c1 * s1;
            float c3 = c2 * c1 - s2 * s1, s3 = c2 * s1 + s2 * c1;
            float t1r = ar + dr, t1i = ai + di;
            re[PIDX(k + 2048)] = t1r * c1 - t1i * s1; im[PIDX(k + 2048)] = t1r * s1 + t1i * c1;
            float t2r = ar - cr, t2i = ai - ci;
            re[PIDX(k + 4096)] = t2r * c2 - t2i * s2; im[PIDX(k + 4096)] = t2r * s2 + t2i * c2;
            float t3r = ar - dr, t3i = ai - di;
            re[PIDX(k + 6144)] = t3r * c3 - t3i * s3; im[PIDX(k + 6144)] = t3r * s3 + t3i * c3;
            float tc = ck * JR - sk * JI; sk = ck * JI + sk * JR; ck = tc;
        }
    }
    __syncthreads();
    pass16_fwd<2048>(re, im, tid);
    __syncthreads();
    pass16_fwd<128>(re, im, tid);
    __syncthreads();
    {   // Z tail + pointwise (af in regs, 1/N fused) + inverse head
        const int base = tid * 16;
        float zr[16], zi[16];
#pragma unroll
        for (int c = 0; c < 16; ++c) { int idx = PIDX(base + c); zr[c] = re[idx]; zi[c] = im[idx]; }
        fwd8(zr, zi, 0); fwd8(zr, zi, 8);
        const float inv = 1.0f / (float)N_FFT;
#pragma unroll
        for (int c = 0; c < 16; ++c) {
            float xr = zr[c], xi_ = zi[c];
            zr[c] = (xr * afr[c] - xi_ * afi[c]) * inv;
            zi[c] = (xr * afi[c] + xi_ * afr[c]) * inv;
        }
        inv8(zr, zi, 0); inv8(zr, zi, 8);
#pragma unroll
        for (int c = 0; c < 16; ++c) { int idx = PIDX(base + c); re[idx] = zr[c]; im[idx] = zi[c]; }
    }
    __syncthreads();
    pass16_inv<128>(re, im, tid);
    __syncthreads();
    pass16_inv<2048>(re, im, tid);
    __syncthreads();
    {   // fused final inverse stage (m=8192): store only [0,4096)
        float2* dst = out_t2 + (size_t)hd * N_SEQ;
        float ck, sk;
        __sincosf(6.283185307179586f / 8192.f * (float)tid, &sk, &ck);
        const float JcR = 0.9238795325f, JcI = 0.3826834324f;
#pragma unroll
        for (int pp = 0; pp < 4; ++pp) {
            int k = pp * FT + tid;
            float c1 = ck, s1 = sk;
            float c2 = c1 * c1 - s1 * s1, s2 = 2.f * c1 * s1;
            float c3 = c2 * c1 - s2 * s1, s3 = c2 * s1 + s2 * c1;
            float t0r = re[PIDX(k)],        t0i = im[PIDX(k)];
            float y1r = re[PIDX(k + 2048)], y1i = im[PIDX(k + 2048)];
            float y2r = re[PIDX(k + 4096)], y2i = im[PIDX(k + 4096)];
            float y3r = re[PIDX(k + 6144)], y3i = im[PIDX(k + 6144)];
            float t1r = y1r * c1 - y1i * s1, t1i = y1r * s1 + y1i * c1;
            float t2r = y2r * c2 - y2i * s2, t2i = y2r * s2 + y2i * c2;
            float t3r = y3r * c3 - y3i * s3, t3i = y3r * s3 + y3i * c3;
            float pr = t0r + t2r, pi = t0i + t2i;
            float qr = t0r - t2r, qi = t0i - t2i;
            float rr = t1r + t3r, ri = t1i + t3i;
            float sr = -(t1i - t3i), si = t1r - t3r;
            dst[k]        = make_float2(pr + rr, pi + ri);
            dst[k + 2048] = make_float2(qr + sr, qi + si);
            float tc = ck * JcR - sk * JcI; sk = ck * JcI + sk * JcR; ck = tc;
        }
    }
}

// ========== transpose out: out_t2[hd][n] -> out (2,8,N,64) ==========
__global__ __launch_bounds__(256) void transpose_o_kernel(const float2* __restrict__ out_t2,
                                                          float* __restrict__ out)
{
    __shared__ float t0[64][65];
    __shared__ float t1[64][65];
    int h = blockIdx.x >> 6;
    int nb = blockIdx.x & 63;
    int lx = threadIdx.x & 63;
    int ly = threadIdx.x >> 6;
    for (int r = ly; r < 64; r += 4) {
        float2 v = out_t2[(size_t)(h * 64 + r) * N_SEQ + nb * 64 + lx];
        t0[r][lx] = v.x;
        t1[r][lx] = v.y;
    }
    __syncthreads();
    float* d0 = out + ((size_t)h * N_SEQ + nb * 64) * 64;
    float* d1 = out + ((size_t)(8 + h) * N_SEQ + nb * 64) * 64;
    for (int r = ly; r < 64; r += 4) {
        d0[r * 64 + lx] = t0[lx][r];
        d1[r * 64 + lx] = t1[lx][r];
    }
}

extern "C" void kernel_launch(void* const* d_in, const int* in_sizes, int n_in,
                              void* d_out, int out_size, void* d_ws, size_t ws_size,
                              hipStream_t stream)
{
    const float* x     = (const float*)d_in[0];
    const float* w_in  = (const float*)d_in[1];
    const float* b_in  = (const float*)d_in[2];
    const float* w_hid = (const float*)d_in[3];
    const float* b_hid = (const float*)d_in[4];
    const float* w_out = (const float*)d_in[5];
    const float* b_out = (const float*)d_in[6];
    float* out = (float*)d_out;

    char* ws = (char*)d_ws;
    float2* xt2    = (float2*)ws;                               // 16 MB
    float*  a_t    = (float*)(ws + (size_t)16 * 1024 * 1024);   // 16 MB
    float2* out_t2 = (float2*)(ws + (size_t)32 * 1024 * 1024);  // 16 MB

    prep_kernel<<<640, 512, 0, stream>>>(x, w_in, b_in, w_hid, b_hid, w_out, b_out,
                                         a_t, xt2);
    conv_kernel<<<512, FT, 0, stream>>>(a_t, xt2, out_t2);
    transpose_o_kernel<<<512, 256, 0, stream>>>(out_t2, out);
}

// Round 7
// 144.336 us; speedup vs baseline: 2.1704x; 1.0470x over previous
//
#include <hip/hip_runtime.h>

#define N_SEQ 4096
#define N_FFT 8192
#define LAYERS 3
#define FT 512                 // threads per FFT block
#define PIDX(i) ((i) + ((i) >> 5))   // +1 word per 32 -> all passes 2-way (free)

// =============== radix-16 pass: two DIF stages (M then M/4) in registers ===============
template<int M>
__device__ inline void pass16_fwd(float* re, float* im, int tid)
{
    const int Q = M >> 4;
    const int j = tid & (Q - 1);
    const int G = tid / Q;
    const int base = G * M + j;
    const float KR[4] = {1.f, 0.9238795325f, 0.7071067812f, 0.3826834324f};
    const float KI[4] = {0.f, -0.3826834324f, -0.7071067812f, -0.9238795325f};
    float xr[4][4], xi[4][4];
#pragma unroll
    for (int a = 0; a < 4; ++a)
#pragma unroll
        for (int b = 0; b < 4; ++b) {
            int idx = PIDX(base + a * (M >> 2) + b * Q);
            xr[a][b] = re[idx]; xi[a][b] = im[idx];
        }
    float cj, sj;
    __sincosf(-6.283185307179586f / (float)M * (float)j, &sj, &cj);
#pragma unroll
    for (int b = 0; b < 4; ++b) {
        float c1 = cj * KR[b] - sj * KI[b];
        float s1 = cj * KI[b] + sj * KR[b];
        float c2 = c1 * c1 - s1 * s1, s2 = 2.f * c1 * s1;
        float c3 = c2 * c1 - s2 * s1, s3 = c2 * s1 + s2 * c1;
        float ar = xr[0][b] + xr[2][b], ai = xi[0][b] + xi[2][b];
        float br = xr[0][b] - xr[2][b], bi = xi[0][b] - xi[2][b];
        float cr = xr[1][b] + xr[3][b], ci = xi[1][b] + xi[3][b];
        float dr = xi[1][b] - xi[3][b], di = -(xr[1][b] - xr[3][b]);
        xr[0][b] = ar + cr;               xi[0][b] = ai + ci;
        float t1r = br + dr, t1i = bi + di;
        xr[1][b] = t1r * c1 - t1i * s1;   xi[1][b] = t1r * s1 + t1i * c1;
        float t2r = ar - cr, t2i = ai - ci;
        xr[2][b] = t2r * c2 - t2i * s2;   xi[2][b] = t2r * s2 + t2i * c2;
        float t3r = br - dr, t3i = bi - di;
        xr[3][b] = t3r * c3 - t3i * s3;   xi[3][b] = t3r * s3 + t3i * c3;
    }
    {
        float e1c = cj * cj - sj * sj, e1s = 2.f * cj * sj;      // W^{2j}
        float c1 = e1c * e1c - e1s * e1s, s1 = 2.f * e1c * e1s;  // W^{4j}
        float c2 = c1 * c1 - s1 * s1, s2 = 2.f * c1 * s1;
        float c3 = c2 * c1 - s2 * s1, s3 = c2 * s1 + s2 * c1;
#pragma unroll
        for (int a = 0; a < 4; ++a) {
            float ar = xr[a][0] + xr[a][2], ai = xi[a][0] + xi[a][2];
            float br = xr[a][0] - xr[a][2], bi = xi[a][0] - xi[a][2];
            float cr = xr[a][1] + xr[a][3], ci = xi[a][1] + xi[a][3];
            float dr = xi[a][1] - xi[a][3], di = -(xr[a][1] - xr[a][3]);
            xr[a][0] = ar + cr;               xi[a][0] = ai + ci;
            float t1r = br + dr, t1i = bi + di;
            xr[a][1] = t1r * c1 - t1i * s1;   xi[a][1] = t1r * s1 + t1i * c1;
            float t2r = ar - cr, t2i = ai - ci;
            xr[a][2] = t2r * c2 - t2i * s2;   xi[a][2] = t2r * s2 + t2i * c2;
            float t3r = br - dr, t3i = bi - di;
            xr[a][3] = t3r * c3 - t3i * s3;   xi[a][3] = t3r * s3 + t3i * c3;
        }
    }
#pragma unroll
    for (int a = 0; a < 4; ++a)
#pragma unroll
        for (int b = 0; b < 4; ++b) {
            int idx = PIDX(base + a * (M >> 2) + b * Q);
            re[idx] = xr[a][b]; im[idx] = xi[a][b];
        }
}

template<int M>
__device__ inline void pass16_inv(float* re, float* im, int tid)
{
    const int Q = M >> 4;
    const int j = tid & (Q - 1);
    const int G = tid / Q;
    const int base = G * M + j;
    const float KR[4] = {1.f, 0.9238795325f, 0.7071067812f, 0.3826834324f};
    const float KI[4] = {0.f, 0.3826834324f, 0.7071067812f, 0.9238795325f};   // conj
    float xr[4][4], xi[4][4];
#pragma unroll
    for (int a = 0; a < 4; ++a)
#pragma unroll
        for (int b = 0; b < 4; ++b) {
            int idx = PIDX(base + a * (M >> 2) + b * Q);
            xr[a][b] = re[idx]; xi[a][b] = im[idx];
        }
    float cj, sj;
    __sincosf(6.283185307179586f / (float)M * (float)j, &sj, &cj);
    {
        float e1c = cj * cj - sj * sj, e1s = 2.f * cj * sj;
        float c1 = e1c * e1c - e1s * e1s, s1 = 2.f * e1c * e1s;
        float c2 = c1 * c1 - s1 * s1, s2 = 2.f * c1 * s1;
        float c3 = c2 * c1 - s2 * s1, s3 = c2 * s1 + s2 * c1;
#pragma unroll
        for (int a = 0; a < 4; ++a) {
            float t0r = xr[a][0], t0i = xi[a][0];
            float t1r = xr[a][1] * c1 - xi[a][1] * s1, t1i = xr[a][1] * s1 + xi[a][1] * c1;
            float t2r = xr[a][2] * c2 - xi[a][2] * s2, t2i = xr[a][2] * s2 + xi[a][2] * c2;
            float t3r = xr[a][3] * c3 - xi[a][3] * s3, t3i = xr[a][3] * s3 + xi[a][3] * c3;
            float pr = t0r + t2r, pi = t0i + t2i;
            float qr = t0r - t2r, qi = t0i - t2i;
            float rr = t1r + t3r, ri = t1i + t3i;
            float sr = -(t1i - t3i), si = t1r - t3r;
            xr[a][0] = pr + rr; xi[a][0] = pi + ri;
            xr[a][1] = qr + sr; xi[a][1] = qi + si;
            xr[a][2] = pr - rr; xi[a][2] = pi - ri;
            xr[a][3] = qr - sr; xi[a][3] = qi - si;
        }
    }
#pragma unroll
    for (int b = 0; b < 4; ++b) {
        float c1 = cj * KR[b] - sj * KI[b];
        float s1 = cj * KI[b] + sj * KR[b];
        float c2 = c1 * c1 - s1 * s1, s2 = 2.f * c1 * s1;
        float c3 = c2 * c1 - s2 * s1, s3 = c2 * s1 + s2 * c1;
        float t0r = xr[0][b], t0i = xi[0][b];
        float t1r = xr[1][b] * c1 - xi[1][b] * s1, t1i = xr[1][b] * s1 + xi[1][b] * c1;
        float t2r = xr[2][b] * c2 - xi[2][b] * s2, t2i = xr[2][b] * s2 + xi[2][b] * c2;
        float t3r = xr[3][b] * c3 - xi[3][b] * s3, t3i = xr[3][b] * s3 + xi[3][b] * c3;
        float pr = t0r + t2r, pi = t0i + t2i;
        float qr = t0r - t2r, qi = t0i - t2i;
        float rr = t1r + t3r, ri = t1i + t3i;
        float sr = -(t1i - t3i), si = t1r - t3r;
        xr[0][b] = pr + rr; xi[0][b] = pi + ri;
        xr[1][b] = qr + sr; xi[1][b] = qi + si;
        xr[2][b] = pr - rr; xi[2][b] = pi - ri;
        xr[3][b] = qr - sr; xi[3][b] = qi - si;
    }
#pragma unroll
    for (int a = 0; a < 4; ++a)
#pragma unroll
        for (int b = 0; b < 4; ++b) {
            int idx = PIDX(base + a * (M >> 2) + b * Q);
            re[idx] = xr[a][b]; im[idx] = xi[a][b];
        }
}

// ======= radix-8 tail (stage m=8 + r2), contiguous 8 points, constant twiddles =======
__device__ inline void fwd8(float* zr, float* zi, int o)
{
    const float R = 0.70710678118654752f;
    {
        float ar = zr[o] + zr[o+4], ai = zi[o] + zi[o+4];
        float br = zr[o] - zr[o+4], bi = zi[o] - zi[o+4];
        float cr = zr[o+2] + zr[o+6], ci = zi[o+2] + zi[o+6];
        float dr = zi[o+2] - zi[o+6], di = -(zr[o+2] - zr[o+6]);
        zr[o]   = ar + cr; zi[o]   = ai + ci;
        zr[o+2] = br + dr; zi[o+2] = bi + di;
        zr[o+4] = ar - cr; zi[o+4] = ai - ci;
        zr[o+6] = br - dr; zi[o+6] = bi - di;
    }
    {
        float ar = zr[o+1] + zr[o+5], ai = zi[o+1] + zi[o+5];
        float br = zr[o+1] - zr[o+5], bi = zi[o+1] - zi[o+5];
        float cr = zr[o+3] + zr[o+7], ci = zi[o+3] + zi[o+7];
        float dr = zi[o+3] - zi[o+7], di = -(zr[o+3] - zr[o+7]);
        zr[o+1] = ar + cr; zi[o+1] = ai + ci;
        float t1r = br + dr, t1i = bi + di;
        zr[o+3] = R * (t1r + t1i); zi[o+3] = R * (t1i - t1r);
        float t2r = ar - cr, t2i = ai - ci;
        zr[o+5] = t2i;  zi[o+5] = -t2r;
        float t3r = br - dr, t3i = bi - di;
        zr[o+7] = R * (t3i - t3r); zi[o+7] = -R * (t3r + t3i);
    }
#pragma unroll
    for (int p = 0; p < 8; p += 2) {
        float ur = zr[o+p], ui = zi[o+p], vr = zr[o+p+1], vi = zi[o+p+1];
        zr[o+p]   = ur + vr; zi[o+p]   = ui + vi;
        zr[o+p+1] = ur - vr; zi[o+p+1] = ui - vi;
    }
}

__device__ inline void inv8(float* zr, float* zi, int o)
{
    const float R = 0.70710678118654752f;
#pragma unroll
    for (int p = 0; p < 8; p += 2) {
        float ur = zr[o+p], ui = zi[o+p], vr = zr[o+p+1], vi = zi[o+p+1];
        zr[o+p]   = ur + vr; zi[o+p]   = ui + vi;
        zr[o+p+1] = ur - vr; zi[o+p+1] = ui - vi;
    }
    {
        float t0r = zr[o],   t0i = zi[o];
        float t1r = zr[o+2], t1i = zi[o+2];
        float t2r = zr[o+4], t2i = zi[o+4];
        float t3r = zr[o+6], t3i = zi[o+6];
        float pr = t0r + t2r, pi = t0i + t2i;
        float qr = t0r - t2r, qi = t0i - t2i;
        float rr = t1r + t3r, ri = t1i + t3i;
        float sr = -(t1i - t3i), si = t1r - t3r;
        zr[o]   = pr + rr; zi[o]   = pi + ri;
        zr[o+2] = qr + sr; zi[o+2] = qi + si;
        zr[o+4] = pr - rr; zi[o+4] = pi - ri;
        zr[o+6] = qr - sr; zi[o+6] = qi - si;
    }
    {
        float t0r = zr[o+1], t0i = zi[o+1];
        float yr = zr[o+3], yi = zi[o+3];
        float t1r = R * (yr - yi), t1i = R * (yr + yi);
        yr = zr[o+5]; yi = zi[o+5];
        float t2r = -yi, t2i = yr;
        yr = zr[o+7]; yi = zi[o+7];
        float t3r = -R * (yr + yi), t3i = R * (yr - yi);
        float pr = t0r + t2r, pi = t0i + t2i;
        float qr = t0r - t2r, qi = t0i - t2i;
        float rr = t1r + t3r, ri = t1i + t3i;
        float sr = -(t1i - t3i), si = t1r - t3r;
        zr[o+1] = pr + rr; zi[o+1] = pi + ri;
        zr[o+3] = qr + sr; zi[o+3] = qi + si;
        zr[o+5] = pr - rr; zi[o+5] = pi - ri;
        zr[o+7] = qr - sr; zi[o+7] = qi - si;
    }
}

// ============ prep: [blocks 0..511] RPE (pos-tile x chunk-pair) -> a_t
//              [blocks 512..1023] transpose x -> xt2 ============
// launch_bounds (512,4): VGPR cap 128 -- round 6's plain (512) squeezed to 32 VGPRs
// and spilled the inner GEMM loop to scratch (45us, VALUBusy 12%).
__global__ __launch_bounds__(512, 4) void prep_kernel(
    const float* __restrict__ x,
    const float* __restrict__ w_in, const float* __restrict__ b_in,
    const float* __restrict__ w_hid, const float* __restrict__ b_hid,
    const float* __restrict__ w_out, const float* __restrict__ b_out,
    float* __restrict__ a_t, float2* __restrict__ xt2)
{
    __shared__ __align__(16) char smem[35328];
    const int tid = threadIdx.x;

    if (blockIdx.x >= 512) {
        // ---- transpose x: (2,8,N,64) -> xt2[hd][n] = (x_b0, x_b1) ----
        float (*t0)[65] = (float (*)[65])smem;
        float (*t1)[65] = (float (*)[65])(smem + 16640);
        int bb = blockIdx.x - 512;
        int h = bb >> 6;
        int nb = bb & 63;
        int lx = tid & 63;
        int ly = tid >> 6;          // 0..7
        const float* s0 = x + ((size_t)h * N_SEQ + nb * 64) * 64;
        const float* s1 = x + ((size_t)(8 + h) * N_SEQ + nb * 64) * 64;
        for (int r = ly; r < 64; r += 8) {
            t0[r][lx] = s0[r * 64 + lx];
            t1[r][lx] = s1[r * 64 + lx];
        }
        __syncthreads();
        for (int r = ly; r < 64; r += 8) {
            float2* dst = xt2 + (size_t)(h * 64 + r) * N_SEQ + nb * 64;
            dst[lx] = make_float2(t0[lx][r], t1[lx][r]);
        }
        return;
    }

    // ---- RPE: block = (pos-tile pt of 64, chunk-pair cp); hidden chain recomputed
    //      per chunk-pair (4x redundant, buys 4x block parallelism) ----
    float4* wl        = (float4*)smem;                     // 16 KB
    float (*ubuf)[65] = (float (*)[65])(smem + 16384);     // 16640 B
    float (*sums)[9]  = (float (*)[9])(smem + 33024);      // 2304 B
    const int pt  = blockIdx.x >> 2;
    const int cp  = blockIdx.x & 3;
    const int p   = tid & 63;
    const int oct = tid >> 6;
    const int pos = pt * 64 + p;

    float v;
    if (pos == 0 || pos == N_SEQ) v = 1.0f;
    else if (pos < N_SEQ)         v = 1.0f / (float)(pos + 1);
    else                          v = -1.0f / (float)(2 * N_SEQ + 1 - pos);

    float h[8];
#pragma unroll
    for (int i = 0; i < 8; ++i) {
        int f = oct * 8 + i;
        h[i] = v * w_in[f] + b_in[f];
    }
    for (int L = 0; L < LAYERS; ++L) {
        const float4* wsrc = (const float4*)(w_hid + L * 4096);
        wl[tid] = wsrc[tid];
        wl[tid + 512] = wsrc[tid + 512];
        float s = 0.f;
#pragma unroll
        for (int i = 0; i < 8; ++i) s += h[i] * h[i];
        sums[p][oct] = s;
        __syncthreads();
        float tot = 0.f;
#pragma unroll
        for (int g = 0; g < 8; ++g) tot += sums[p][g];
        float r = rsqrtf(tot * (1.f / 64.f) + 1e-8f);
#pragma unroll
        for (int i = 0; i < 8; ++i)
            ubuf[p][oct * 8 + i] = fmaxf(h[i] * r, 0.f);
        __syncthreads();
        float acc[8];
#pragma unroll
        for (int i = 0; i < 8; ++i) acc[i] = b_hid[L * 64 + oct * 8 + i];
#pragma unroll 4
        for (int j = 0; j < 64; ++j) {
            float uj = ubuf[p][j];
            float4 w0 = wl[j * 16 + oct * 2];
            float4 w1 = wl[j * 16 + oct * 2 + 1];
            acc[0] = fmaf(uj, w0.x, acc[0]); acc[1] = fmaf(uj, w0.y, acc[1]);
            acc[2] = fmaf(uj, w0.z, acc[2]); acc[3] = fmaf(uj, w0.w, acc[3]);
            acc[4] = fmaf(uj, w1.x, acc[4]); acc[5] = fmaf(uj, w1.y, acc[5]);
            acc[6] = fmaf(uj, w1.z, acc[6]); acc[7] = fmaf(uj, w1.w, acc[7]);
        }
#pragma unroll
        for (int i = 0; i < 8; ++i) h[i] = acc[i];
        __syncthreads();
    }
    {
        float s = 0.f;
#pragma unroll
        for (int i = 0; i < 8; ++i) s += h[i] * h[i];
        sums[p][oct] = s;
        __syncthreads();
        float tot = 0.f;
#pragma unroll
        for (int g = 0; g < 8; ++g) tot += sums[p][g];
        float r = rsqrtf(tot * (1.f / 64.f) + 1e-8f);
#pragma unroll
        for (int i = 0; i < 8; ++i)
            ubuf[p][oct * 8 + i] = fmaxf(h[i] * r, 0.f);
        __syncthreads();
    }
    // this block's two output chunks
    for (int cc = 0; cc < 2; ++cc) {
        const int c = cp * 2 + cc;
        float4 wreg0, wreg1;
        {
            int i4 = tid;
            wreg0 = *(const float4*)(w_out + (i4 >> 4) * 512 + c * 64 + (i4 & 15) * 4);
            i4 = tid + 512;
            wreg1 = *(const float4*)(w_out + (i4 >> 4) * 512 + c * 64 + (i4 & 15) * 4);
        }
        __syncthreads();   // prior round's wl reads done
        wl[tid] = wreg0;
        wl[tid + 512] = wreg1;
        __syncthreads();
        float acc[8];
#pragma unroll
        for (int i = 0; i < 8; ++i) acc[i] = b_out[c * 64 + oct * 8 + i];
#pragma unroll 4
        for (int j = 0; j < 64; ++j) {
            float uj = ubuf[p][j];
            float4 w0 = wl[j * 16 + oct * 2];
            float4 w1 = wl[j * 16 + oct * 2 + 1];
            acc[0] = fmaf(uj, w0.x, acc[0]); acc[1] = fmaf(uj, w0.y, acc[1]);
            acc[2] = fmaf(uj, w0.z, acc[2]); acc[3] = fmaf(uj, w0.w, acc[3]);
            acc[4] = fmaf(uj, w1.x, acc[4]); acc[5] = fmaf(uj, w1.y, acc[5]);
            acc[6] = fmaf(uj, w1.z, acc[6]); acc[7] = fmaf(uj, w1.w, acc[7]);
        }
#pragma unroll
        for (int i = 0; i < 8; ++i)
            a_t[(size_t)(c * 64 + oct * 8 + i) * N_FFT + pos] = acc[i];
    }
}

// ========== conv: A-FFT (spectrum kept in regs) + z-FFT + mult + iFFT ==========
__global__ __launch_bounds__(FT, 2) void conv_kernel(const float* __restrict__ a_t,
                                                     const float2* __restrict__ xt2,
                                                     float2* __restrict__ out_t2)
{
    __shared__ float re[8448];
    __shared__ float im[8448];
    const int tid = threadIdx.x;
    const int hd = blockIdx.x;
    const float JR = 0.9238795325f;        // e^{-2pi i/16}
    const float JI = -0.3826834324f;

    // ---- A forward: fused m=8192 stage (real input) ----
    {
        const float* src = a_t + (size_t)hd * N_FFT;
        float ck, sk;
        __sincosf(-6.283185307179586f / 8192.f * (float)tid, &sk, &ck);
#pragma unroll
        for (int pp = 0; pp < 4; ++pp) {
            int k = pp * FT + tid;
            float x0 = src[k], x1 = src[k + 2048], x2 = src[k + 4096], x3 = src[k + 6144];
            float ar = x0 + x2, br = x0 - x2;
            float cr = x1 + x3, e = x1 - x3;
            re[PIDX(k)] = ar + cr; im[PIDX(k)] = 0.f;
            float c1 = ck, s1 = sk;
            float c2 = c1 * c1 - s1 * s1, s2 = 2.f * c1 * s1;
            float c3 = c2 * c1 - s2 * s1, s3 = c2 * s1 + s2 * c1;
            re[PIDX(k + 2048)] = br * c1 + e * s1;  im[PIDX(k + 2048)] = br * s1 - e * c1;
            float t2r = ar - cr;
            re[PIDX(k + 4096)] = t2r * c2;          im[PIDX(k + 4096)] = t2r * s2;
            re[PIDX(k + 6144)] = br * c3 - e * s3;  im[PIDX(k + 6144)] = br * s3 + e * c3;
            float tc = ck * JR - sk * JI; sk = ck * JI + sk * JR; ck = tc;  // W^{k+512}
        }
    }
    __syncthreads();
    pass16_fwd<2048>(re, im, tid);
    __syncthreads();
    pass16_fwd<128>(re, im, tid);
    __syncthreads();
    // ---- A tail: unscaled spectrum stays in registers (1/N folded in later) ----
    float afr[16], afi[16];
    {
        const int base = tid * 16;
#pragma unroll
        for (int c = 0; c < 16; ++c) { int idx = PIDX(base + c); afr[c] = re[idx]; afi[c] = im[idx]; }
        fwd8(afr, afi, 0); fwd8(afr, afi, 8);
    }
    __syncthreads();
    // ---- Z forward: fused m=8192 stage (packed complex, x2=x3=0) ----
    {
        const float2* src = xt2 + (size_t)hd * N_SEQ;
        float ck, sk;
        __sincosf(-6.283185307179586f / 8192.f * (float)tid, &sk, &ck);
#pragma unroll
        for (int pp = 0; pp < 4; ++pp) {
            int k = pp * FT + tid;
            float2 z0 = src[k], z1 = src[k + 2048];
            float ar = z0.x, ai = z0.y;
            float cr = z1.x, ci = z1.y;
            float dr = z1.y, di = -z1.x;
            re[PIDX(k)] = ar + cr; im[PIDX(k)] = ai + ci;
            float c1 = ck, s1 = sk;
            float c2 = c1 * c1 - s1 * s1, s2 = 2.f * c1 * s1;
            float c3 = c2 * c1 - s2 * s1, s3 = c2 * s1 + s2 * c1;
            float t1r = ar + dr, t1i = ai + di;
            re[PIDX(k + 2048)] = t1r * c1 - t1i * s1; im[PIDX(k + 2048)] = t1r * s1 + t1i * c1;
            float t2r = ar - cr, t2i = ai - ci;
            re[PIDX(k + 4096)] = t2r * c2 - t2i * s2; im[PIDX(k + 4096)] = t2r * s2 + t2i * c2;
            float t3r = ar - dr, t3i = ai - di;
            re[PIDX(k + 6144)] = t3r * c3 - t3i * s3; im[PIDX(k + 6144)] = t3r * s3 + t3i * c3;
            float tc = ck * JR - sk * JI; sk = ck * JI + sk * JR; ck = tc;
        }
    }
    __syncthreads();
    pass16_fwd<2048>(re, im, tid);
    __syncthreads();
    pass16_fwd<128>(re, im, tid);
    __syncthreads();
    {   // Z tail + pointwise (af in regs, 1/N fused) + inverse head
        const int base = tid * 16;
        float zr[16], zi[16];
#pragma unroll
        for (int c = 0; c < 16; ++c) { int idx = PIDX(base + c); zr[c] = re[idx]; zi[c] = im[idx]; }
        fwd8(zr, zi, 0); fwd8(zr, zi, 8);
        const float inv = 1.0f / (float)N_FFT;
#pragma unroll
        for (int c = 0; c < 16; ++c) {
            float xr = zr[c], xi_ = zi[c];
            zr[c] = (xr * afr[c] - xi_ * afi[c]) * inv;
            zi[c] = (xr * afi[c] + xi_ * afr[c]) * inv;
        }
        inv8(zr, zi, 0); inv8(zr, zi, 8);
#pragma unroll
        for (int c = 0; c < 16; ++c) { int idx = PIDX(base + c); re[idx] = zr[c]; im[idx] = zi[c]; }
    }
    __syncthreads();
    pass16_inv<128>(re, im, tid);
    __syncthreads();
    pass16_inv<2048>(re, im, tid);
    __syncthreads();
    {   // fused final inverse stage (m=8192): store only [0,4096)
        float2* dst = out_t2 + (size_t)hd * N_SEQ;
        float ck, sk;
        __sincosf(6.283185307179586f / 8192.f * (float)tid, &sk, &ck);
        const float JcR = 0.9238795325f, JcI = 0.3826834324f;
#pragma unroll
        for (int pp = 0; pp < 4; ++pp) {
            int k = pp * FT + tid;
            float c1 = ck, s1 = sk;
            float c2 = c1 * c1 - s1 * s1, s2 = 2.f * c1 * s1;
            float c3 = c2 * c1 - s2 * s1, s3 = c2 * s1 + s2 * c1;
            float t0r = re[PIDX(k)],        t0i = im[PIDX(k)];
            float y1r = re[PIDX(k + 2048)], y1i = im[PIDX(k + 2048)];
            float y2r = re[PIDX(k + 4096)], y2i = im[PIDX(k + 4096)];
            float y3r = re[PIDX(k + 6144)], y3i = im[PIDX(k + 6144)];
            float t1r = y1r * c1 - y1i * s1, t1i = y1r * s1 + y1i * c1;
            float t2r = y2r * c2 - y2i * s2, t2i = y2r * s2 + y2i * c2;
            float t3r = y3r * c3 - y3i * s3, t3i = y3r * s3 + y3i * c3;
            float pr = t0r + t2r, pi = t0i + t2i;
            float qr = t0r - t2r, qi = t0i - t2i;
            float rr = t1r + t3r, ri = t1i + t3i;
            float sr = -(t1i - t3i), si = t1r - t3r;
            dst[k]        = make_float2(pr + rr, pi + ri);
            dst[k + 2048] = make_float2(qr + sr, qi + si);
            float tc = ck * JcR - sk * JcI; sk = ck * JcI + sk * JcR; ck = tc;
        }
    }
}

// ========== transpose out: out_t2[hd][n] -> out (2,8,N,64) ==========
__global__ __launch_bounds__(256) void transpose_o_kernel(const float2* __restrict__ out_t2,
                                                          float* __restrict__ out)
{
    __shared__ float t0[64][65];
    __shared__ float t1[64][65];
    int h = blockIdx.x >> 6;
    int nb = blockIdx.x & 63;
    int lx = threadIdx.x & 63;
    int ly = threadIdx.x >> 6;
    for (int r = ly; r < 64; r += 4) {
        float2 v = out_t2[(size_t)(h * 64 + r) * N_SEQ + nb * 64 + lx];
        t0[r][lx] = v.x;
        t1[r][lx] = v.y;
    }
    __syncthreads();
    float* d0 = out + ((size_t)h * N_SEQ + nb * 64) * 64;
    float* d1 = out + ((size_t)(8 + h) * N_SEQ + nb * 64) * 64;
    for (int r = ly; r < 64; r += 4) {
        d0[r * 64 + lx] = t0[lx][r];
        d1[r * 64 + lx] = t1[lx][r];
    }
}

extern "C" void kernel_launch(void* const* d_in, const int* in_sizes, int n_in,
                              void* d_out, int out_size, void* d_ws, size_t ws_size,
                              hipStream_t stream)
{
    const float* x     = (const float*)d_in[0];
    const float* w_in  = (const float*)d_in[1];
    const float* b_in  = (const float*)d_in[2];
    const float* w_hid = (const float*)d_in[3];
    const float* b_hid = (const float*)d_in[4];
    const float* w_out = (const float*)d_in[5];
    const float* b_out = (const float*)d_in[6];
    float* out = (float*)d_out;

    char* ws = (char*)d_ws;
    float2* xt2    = (float2*)ws;                               // 16 MB
    float*  a_t    = (float*)(ws + (size_t)16 * 1024 * 1024);   // 16 MB
    float2* out_t2 = (float2*)(ws + (size_t)32 * 1024 * 1024);  // 16 MB

    prep_kernel<<<1024, 512, 0, stream>>>(x, w_in, b_in, w_hid, b_hid, w_out, b_out,
                                          a_t, xt2);
    conv_kernel<<<512, FT, 0, stream>>>(a_t, xt2, out_t2);
    transpose_o_kernel<<<512, 256, 0, stream>>>(out_t2, out);
}

// Round 8
// 144.211 us; speedup vs baseline: 2.1723x; 1.0009x over previous
//
#include <hip/hip_runtime.h>

#define N_SEQ 4096
#define N_FFT 8192
#define LAYERS 3
#define FT 512                 // threads per FFT block
#define PIDX(i) ((i) + ((i) >> 5))   // +1 word per 32 -> all passes 2-way (free)

// =============== radix-16 pass: two DIF stages (M then M/4) in registers ===============
template<int M>
__device__ inline void pass16_fwd(float* re, float* im, int tid)
{
    const int Q = M >> 4;
    const int j = tid & (Q - 1);
    const int G = tid / Q;
    const int base = G * M + j;
    const float KR[4] = {1.f, 0.9238795325f, 0.7071067812f, 0.3826834324f};
    const float KI[4] = {0.f, -0.3826834324f, -0.7071067812f, -0.9238795325f};
    float xr[4][4], xi[4][4];
#pragma unroll
    for (int a = 0; a < 4; ++a)
#pragma unroll
        for (int b = 0; b < 4; ++b) {
            int idx = PIDX(base + a * (M >> 2) + b * Q);
            xr[a][b] = re[idx]; xi[a][b] = im[idx];
        }
    float cj, sj;
    __sincosf(-6.283185307179586f / (float)M * (float)j, &sj, &cj);
#pragma unroll
    for (int b = 0; b < 4; ++b) {
        float c1 = cj * KR[b] - sj * KI[b];
        float s1 = cj * KI[b] + sj * KR[b];
        float c2 = c1 * c1 - s1 * s1, s2 = 2.f * c1 * s1;
        float c3 = c2 * c1 - s2 * s1, s3 = c2 * s1 + s2 * c1;
        float ar = xr[0][b] + xr[2][b], ai = xi[0][b] + xi[2][b];
        float br = xr[0][b] - xr[2][b], bi = xi[0][b] - xi[2][b];
        float cr = xr[1][b] + xr[3][b], ci = xi[1][b] + xi[3][b];
        float dr = xi[1][b] - xi[3][b], di = -(xr[1][b] - xr[3][b]);
        xr[0][b] = ar + cr;               xi[0][b] = ai + ci;
        float t1r = br + dr, t1i = bi + di;
        xr[1][b] = t1r * c1 - t1i * s1;   xi[1][b] = t1r * s1 + t1i * c1;
        float t2r = ar - cr, t2i = ai - ci;
        xr[2][b] = t2r * c2 - t2i * s2;   xi[2][b] = t2r * s2 + t2i * c2;
        float t3r = br - dr, t3i = bi - di;
        xr[3][b] = t3r * c3 - t3i * s3;   xi[3][b] = t3r * s3 + t3i * c3;
    }
    {
        float e1c = cj * cj - sj * sj, e1s = 2.f * cj * sj;      // W^{2j}
        float c1 = e1c * e1c - e1s * e1s, s1 = 2.f * e1c * e1s;  // W^{4j}
        float c2 = c1 * c1 - s1 * s1, s2 = 2.f * c1 * s1;
        float c3 = c2 * c1 - s2 * s1, s3 = c2 * s1 + s2 * c1;
#pragma unroll
        for (int a = 0; a < 4; ++a) {
            float ar = xr[a][0] + xr[a][2], ai = xi[a][0] + xi[a][2];
            float br = xr[a][0] - xr[a][2], bi = xi[a][0] - xi[a][2];
            float cr = xr[a][1] + xr[a][3], ci = xi[a][1] + xi[a][3];
            float dr = xi[a][1] - xi[a][3], di = -(xr[a][1] - xr[a][3]);
            xr[a][0] = ar + cr;               xi[a][0] = ai + ci;
            float t1r = br + dr, t1i = bi + di;
            xr[a][1] = t1r * c1 - t1i * s1;   xi[a][1] = t1r * s1 + t1i * c1;
            float t2r = ar - cr, t2i = ai - ci;
            xr[a][2] = t2r * c2 - t2i * s2;   xi[a][2] = t2r * s2 + t2i * c2;
            float t3r = br - dr, t3i = bi - di;
            xr[a][3] = t3r * c3 - t3i * s3;   xi[a][3] = t3r * s3 + t3i * c3;
        }
    }
#pragma unroll
    for (int a = 0; a < 4; ++a)
#pragma unroll
        for (int b = 0; b < 4; ++b) {
            int idx = PIDX(base + a * (M >> 2) + b * Q);
            re[idx] = xr[a][b]; im[idx] = xi[a][b];
        }
}

template<int M>
__device__ inline void pass16_inv(float* re, float* im, int tid)
{
    const int Q = M >> 4;
    const int j = tid & (Q - 1);
    const int G = tid / Q;
    const int base = G * M + j;
    const float KR[4] = {1.f, 0.9238795325f, 0.7071067812f, 0.3826834324f};
    const float KI[4] = {0.f, 0.3826834324f, 0.7071067812f, 0.9238795325f};   // conj
    float xr[4][4], xi[4][4];
#pragma unroll
    for (int a = 0; a < 4; ++a)
#pragma unroll
        for (int b = 0; b < 4; ++b) {
            int idx = PIDX(base + a * (M >> 2) + b * Q);
            xr[a][b] = re[idx]; xi[a][b] = im[idx];
        }
    float cj, sj;
    __sincosf(6.283185307179586f / (float)M * (float)j, &sj, &cj);
    {
        float e1c = cj * cj - sj * sj, e1s = 2.f * cj * sj;
        float c1 = e1c * e1c - e1s * e1s, s1 = 2.f * e1c * e1s;
        float c2 = c1 * c1 - s1 * s1, s2 = 2.f * c1 * s1;
        float c3 = c2 * c1 - s2 * s1, s3 = c2 * s1 + s2 * c1;
#pragma unroll
        for (int a = 0; a < 4; ++a) {
            float t0r = xr[a][0], t0i = xi[a][0];
            float t1r = xr[a][1] * c1 - xi[a][1] * s1, t1i = xr[a][1] * s1 + xi[a][1] * c1;
            float t2r = xr[a][2] * c2 - xi[a][2] * s2, t2i = xr[a][2] * s2 + xi[a][2] * c2;
            float t3r = xr[a][3] * c3 - xi[a][3] * s3, t3i = xr[a][3] * s3 + xi[a][3] * c3;
            float pr = t0r + t2r, pi = t0i + t2i;
            float qr = t0r - t2r, qi = t0i - t2i;
            float rr = t1r + t3r, ri = t1i + t3i;
            float sr = -(t1i - t3i), si = t1r - t3r;
            xr[a][0] = pr + rr; xi[a][0] = pi + ri;
            xr[a][1] = qr + sr; xi[a][1] = qi + si;
            xr[a][2] = pr - rr; xi[a][2] = pi - ri;
            xr[a][3] = qr - sr; xi[a][3] = qi - si;
        }
    }
#pragma unroll
    for (int b = 0; b < 4; ++b) {
        float c1 = cj * KR[b] - sj * KI[b];
        float s1 = cj * KI[b] + sj * KR[b];
        float c2 = c1 * c1 - s1 * s1, s2 = 2.f * c1 * s1;
        float c3 = c2 * c1 - s2 * s1, s3 = c2 * s1 + s2 * c1;
        float t0r = xr[0][b], t0i = xi[0][b];
        float t1r = xr[1][b] * c1 - xi[1][b] * s1, t1i = xr[1][b] * s1 + xi[1][b] * c1;
        float t2r = xr[2][b] * c2 - xi[2][b] * s2, t2i = xr[2][b] * s2 + xi[2][b] * c2;
        float t3r = xr[3][b] * c3 - xi[3][b] * s3, t3i = xr[3][b] * s3 + xi[3][b] * c3;
        float pr = t0r + t2r, pi = t0i + t2i;
        float qr = t0r - t2r, qi = t0i - t2i;
        float rr = t1r + t3r, ri = t1i + t3i;
        float sr = -(t1i - t3i), si = t1r - t3r;
        xr[0][b] = pr + rr; xi[0][b] = pi + ri;
        xr[1][b] = qr + sr; xi[1][b] = qi + si;
        xr[2][b] = pr - rr; xi[2][b] = pi - ri;
        xr[3][b] = qr - sr; xi[3][b] = qi - si;
    }
#pragma unroll
    for (int a = 0; a < 4; ++a)
#pragma unroll
        for (int b = 0; b < 4; ++b) {
            int idx = PIDX(base + a * (M >> 2) + b * Q);
            re[idx] = xr[a][b]; im[idx] = xi[a][b];
        }
}

// ======= radix-8 tail (stage m=8 + r2), contiguous 8 points, constant twiddles =======
__device__ inline void fwd8(float* zr, float* zi, int o)
{
    const float R = 0.70710678118654752f;
    {
        float ar = zr[o] + zr[o+4], ai = zi[o] + zi[o+4];
        float br = zr[o] - zr[o+4], bi = zi[o] - zi[o+4];
        float cr = zr[o+2] + zr[o+6], ci = zi[o+2] + zi[o+6];
        float dr = zi[o+2] - zi[o+6], di = -(zr[o+2] - zr[o+6]);
        zr[o]   = ar + cr; zi[o]   = ai + ci;
        zr[o+2] = br + dr; zi[o+2] = bi + di;
        zr[o+4] = ar - cr; zi[o+4] = ai - ci;
        zr[o+6] = br - dr; zi[o+6] = bi - di;
    }
    {
        float ar = zr[o+1] + zr[o+5], ai = zi[o+1] + zi[o+5];
        float br = zr[o+1] - zr[o+5], bi = zi[o+1] - zi[o+5];
        float cr = zr[o+3] + zr[o+7], ci = zi[o+3] + zi[o+7];
        float dr = zi[o+3] - zi[o+7], di = -(zr[o+3] - zr[o+7]);
        zr[o+1] = ar + cr; zi[o+1] = ai + ci;
        float t1r = br + dr, t1i = bi + di;
        zr[o+3] = R * (t1r + t1i); zi[o+3] = R * (t1i - t1r);
        float t2r = ar - cr, t2i = ai - ci;
        zr[o+5] = t2i;  zi[o+5] = -t2r;
        float t3r = br - dr, t3i = bi - di;
        zr[o+7] = R * (t3i - t3r); zi[o+7] = -R * (t3r + t3i);
    }
#pragma unroll
    for (int p = 0; p < 8; p += 2) {
        float ur = zr[o+p], ui = zi[o+p], vr = zr[o+p+1], vi = zi[o+p+1];
        zr[o+p]   = ur + vr; zi[o+p]   = ui + vi;
        zr[o+p+1] = ur - vr; zi[o+p+1] = ui - vi;
    }
}

__device__ inline void inv8(float* zr, float* zi, int o)
{
    const float R = 0.70710678118654752f;
#pragma unroll
    for (int p = 0; p < 8; p += 2) {
        float ur = zr[o+p], ui = zi[o+p], vr = zr[o+p+1], vi = zi[o+p+1];
        zr[o+p]   = ur + vr; zi[o+p]   = ui + vi;
        zr[o+p+1] = ur - vr; zi[o+p+1] = ui - vi;
    }
    {
        float t0r = zr[o],   t0i = zi[o];
        float t1r = zr[o+2], t1i = zi[o+2];
        float t2r = zr[o+4], t2i = zi[o+4];
        float t3r = zr[o+6], t3i = zi[o+6];
        float pr = t0r + t2r, pi = t0i + t2i;
        float qr = t0r - t2r, qi = t0i - t2i;
        float rr = t1r + t3r, ri = t1i + t3i;
        float sr = -(t1i - t3i), si = t1r - t3r;
        zr[o]   = pr + rr; zi[o]   = pi + ri;
        zr[o+2] = qr + sr; zi[o+2] = qi + si;
        zr[o+4] = pr - rr; zi[o+4] = pi - ri;
        zr[o+6] = qr - sr; zi[o+6] = qi - si;
    }
    {
        float t0r = zr[o+1], t0i = zi[o+1];
        float yr = zr[o+3], yi = zi[o+3];
        float t1r = R * (yr - yi), t1i = R * (yr + yi);
        yr = zr[o+5]; yi = zi[o+5];
        float t2r = -yi, t2i = yr;
        yr = zr[o+7]; yi = zi[o+7];
        float t3r = -R * (yr + yi), t3i = R * (yr - yi);
        float pr = t0r + t2r, pi = t0i + t2i;
        float qr = t0r - t2r, qi = t0i - t2i;
        float rr = t1r + t3r, ri = t1i + t3i;
        float sr = -(t1i - t3i), si = t1r - t3r;
        zr[o+1] = pr + rr; zi[o+1] = pi + ri;
        zr[o+3] = qr + sr; zi[o+3] = qi + si;
        zr[o+5] = pr - rr; zi[o+5] = pi - ri;
        zr[o+7] = qr - sr; zi[o+7] = qi - si;
    }
}

// ============ prep: [blocks 0..255] RPE (32 pos/block, all 512 outputs) -> a_t
//              [blocks 256..767] transpose x -> xt2 ============
// LDS layout (RPE): ubuf[32][65] @0 (8320 B) | sums[32][17] @8320 (2176 B)
//                   | weight area @10496 (32 KB)  => 43264 B total
// Out-GEMM: thread = (octet o=tid>>3, pos-group pg=tid&7), acc[8][4] in regs,
// j tiled x16 (w-tile 32 KB). Per wave per j: 2 ds_read_b128 + 4 ds_read_b32
// (~48 cyc) vs 32 fma-insts (64 cyc) -> VALU-bound (round 7 was 3.8 cyc/fma LDS-bound).
__global__ __launch_bounds__(512, 4) void prep_kernel(
    const float* __restrict__ x,
    const float* __restrict__ w_in, const float* __restrict__ b_in,
    const float* __restrict__ w_hid, const float* __restrict__ b_hid,
    const float* __restrict__ w_out, const float* __restrict__ b_out,
    float* __restrict__ a_t, float2* __restrict__ xt2)
{
    __shared__ __align__(16) char smem[43264];
    const int tid = threadIdx.x;

    if (blockIdx.x >= 256) {
        // ---- transpose x: (2,8,N,64) -> xt2[hd][n] = (x_b0, x_b1) ----
        float (*t0)[65] = (float (*)[65])smem;
        float (*t1)[65] = (float (*)[65])(smem + 16640);
        int bb = blockIdx.x - 256;
        int h = bb >> 6;
        int nb = bb & 63;
        int lx = tid & 63;
        int ly = tid >> 6;          // 0..7
        const float* s0 = x + ((size_t)h * N_SEQ + nb * 64) * 64;
        const float* s1 = x + ((size_t)(8 + h) * N_SEQ + nb * 64) * 64;
        for (int r = ly; r < 64; r += 8) {
            t0[r][lx] = s0[r * 64 + lx];
            t1[r][lx] = s1[r * 64 + lx];
        }
        __syncthreads();
        for (int r = ly; r < 64; r += 8) {
            float2* dst = xt2 + (size_t)(h * 64 + r) * N_SEQ + nb * 64;
            dst[lx] = make_float2(t0[lx][r], t1[lx][r]);
        }
        return;
    }

    float (*ubuf)[65] = (float (*)[65])smem;               // [pos][feat]
    float (*sums)[17] = (float (*)[17])(smem + 8320);
    float4* wl        = (float4*)(smem + 10496);           // weight area

    // ---- hidden chain: thread = (p = tid&31, s = tid>>5 feature-quad) ----
    {
        const int p = tid & 31;
        const int s = tid >> 5;       // 0..15, features s*4..s*4+3
        const int pos = blockIdx.x * 32 + p;
        float v;
        if (pos == 0 || pos == N_SEQ) v = 1.0f;
        else if (pos < N_SEQ)         v = 1.0f / (float)(pos + 1);
        else                          v = -1.0f / (float)(2 * N_SEQ + 1 - pos);

        float h[4];
#pragma unroll
        for (int i = 0; i < 4; ++i) {
            int f = s * 4 + i;
            h[i] = v * w_in[f] + b_in[f];
        }
        for (int L = 0; L < LAYERS; ++L) {
            const float4* wsrc = (const float4*)(w_hid + L * 4096);
            wl[tid] = wsrc[tid];
            wl[tid + 512] = wsrc[tid + 512];
            float s2 = h[0]*h[0] + h[1]*h[1] + h[2]*h[2] + h[3]*h[3];
            sums[p][s] = s2;
            __syncthreads();
            float tot = 0.f;
#pragma unroll
            for (int g = 0; g < 16; ++g) tot += sums[p][g];
            float r = rsqrtf(tot * (1.f / 64.f) + 1e-8f);
#pragma unroll
            for (int i = 0; i < 4; ++i)
                ubuf[p][s * 4 + i] = fmaxf(h[i] * r, 0.f);
            __syncthreads();           // ubuf + wl ready
            float acc[4];
#pragma unroll
            for (int i = 0; i < 4; ++i) acc[i] = b_hid[L * 64 + s * 4 + i];
#pragma unroll 8
            for (int j = 0; j < 64; ++j) {
                float uj = ubuf[p][j];
                float4 w = wl[j * 16 + s];
                acc[0] = fmaf(uj, w.x, acc[0]); acc[1] = fmaf(uj, w.y, acc[1]);
                acc[2] = fmaf(uj, w.z, acc[2]); acc[3] = fmaf(uj, w.w, acc[3]);
            }
#pragma unroll
            for (int i = 0; i < 4; ++i) h[i] = acc[i];
            __syncthreads();           // before wl/sums/ubuf overwrite
        }
        // final RMS + relu -> ubuf
        float s2 = h[0]*h[0] + h[1]*h[1] + h[2]*h[2] + h[3]*h[3];
        sums[p][s] = s2;
        __syncthreads();
        float tot = 0.f;
#pragma unroll
        for (int g = 0; g < 16; ++g) tot += sums[p][g];
        float r = rsqrtf(tot * (1.f / 64.f) + 1e-8f);
#pragma unroll
        for (int i = 0; i < 4; ++i)
            ubuf[p][s * 4 + i] = fmaxf(h[i] * r, 0.f);
        __syncthreads();
    }

    // ---- out GEMM: thread = (o = tid>>3 octet, pg = tid&7 pos-group of 4) ----
    {
        const int o  = tid >> 3;
        const int pg = tid & 7;
        const int pos0 = blockIdx.x * 32;
        float4* wt = wl;               // [16][128] float4: row jj = 128 float4
        float acc[8][4];
#pragma unroll
        for (int ii = 0; ii < 8; ++ii) {
            float bo = b_out[o * 8 + ii];
#pragma unroll
            for (int i = 0; i < 4; ++i) acc[ii][i] = bo;
        }
        for (int jc = 0; jc < 4; ++jc) {
            float4 wreg[4];
#pragma unroll
            for (int k = 0; k < 4; ++k) {
                int i4 = k * 512 + tid;           // 0..2047
                int jj = i4 >> 7, f4 = i4 & 127;
                wreg[k] = *(const float4*)(w_out + (jc * 16 + jj) * 512 + f4 * 4);
            }
            __syncthreads();           // prior wt reads done (1st iter: hidden's wl)
#pragma unroll
            for (int k = 0; k < 4; ++k) {
                int i4 = k * 512 + tid;
                wt[i4] = wreg[k];
            }
            __syncthreads();
#pragma unroll
            for (int jj = 0; jj < 16; ++jj) {
                int j = jc * 16 + jj;
                float4 w0 = wt[jj * 128 + o * 2];
                float4 w1 = wt[jj * 128 + o * 2 + 1];
                float u0 = ubuf[pg * 4 + 0][j];
                float u1 = ubuf[pg * 4 + 1][j];
                float u2 = ubuf[pg * 4 + 2][j];
                float u3 = ubuf[pg * 4 + 3][j];
                acc[0][0] = fmaf(u0, w0.x, acc[0][0]); acc[0][1] = fmaf(u1, w0.x, acc[0][1]);
                acc[0][2] = fmaf(u2, w0.x, acc[0][2]); acc[0][3] = fmaf(u3, w0.x, acc[0][3]);
                acc[1][0] = fmaf(u0, w0.y, acc[1][0]); acc[1][1] = fmaf(u1, w0.y, acc[1][1]);
                acc[1][2] = fmaf(u2, w0.y, acc[1][2]); acc[1][3] = fmaf(u3, w0.y, acc[1][3]);
                acc[2][0] = fmaf(u0, w0.z, acc[2][0]); acc[2][1] = fmaf(u1, w0.z, acc[2][1]);
                acc[2][2] = fmaf(u2, w0.z, acc[2][2]); acc[2][3] = fmaf(u3, w0.z, acc[2][3]);
                acc[3][0] = fmaf(u0, w0.w, acc[3][0]); acc[3][1] = fmaf(u1, w0.w, acc[3][1]);
                acc[3][2] = fmaf(u2, w0.w, acc[3][2]); acc[3][3] = fmaf(u3, w0.w, acc[3][3]);
                acc[4][0] = fmaf(u0, w1.x, acc[4][0]); acc[4][1] = fmaf(u1, w1.x, acc[4][1]);
                acc[4][2] = fmaf(u2, w1.x, acc[4][2]); acc[4][3] = fmaf(u3, w1.x, acc[4][3]);
                acc[5][0] = fmaf(u0, w1.y, acc[5][0]); acc[5][1] = fmaf(u1, w1.y, acc[5][1]);
                acc[5][2] = fmaf(u2, w1.y, acc[5][2]); acc[5][3] = fmaf(u3, w1.y, acc[5][3]);
                acc[6][0] = fmaf(u0, w1.z, acc[6][0]); acc[6][1] = fmaf(u1, w1.z, acc[6][1]);
                acc[6][2] = fmaf(u2, w1.z, acc[6][2]); acc[6][3] = fmaf(u3, w1.z, acc[6][3]);
                acc[7][0] = fmaf(u0, w1.w, acc[7][0]); acc[7][1] = fmaf(u1, w1.w, acc[7][1]);
                acc[7][2] = fmaf(u2, w1.w, acc[7][2]); acc[7][3] = fmaf(u3, w1.w, acc[7][3]);
            }
            __syncthreads();           // wt reads done before next stage
        }
#pragma unroll
        for (int ii = 0; ii < 8; ++ii) {
            int f = o * 8 + ii;
#pragma unroll
            for (int i = 0; i < 4; ++i)
                a_t[(size_t)f * N_FFT + pos0 + pg * 4 + i] = acc[ii][i];
        }
    }
}

// ========== conv: A-FFT (spectrum kept in regs) + z-FFT + mult + iFFT ==========
__global__ __launch_bounds__(FT, 2) void conv_kernel(const float* __restrict__ a_t,
                                                     const float2* __restrict__ xt2,
                                                     float2* __restrict__ out_t2)
{
    __shared__ float re[8448];
    __shared__ float im[8448];
    const int tid = threadIdx.x;
    const int hd = blockIdx.x;
    const float JR = 0.9238795325f;        // e^{-2pi i/16}
    const float JI = -0.3826834324f;

    // ---- A forward: fused m=8192 stage (real input) ----
    {
        const float* src = a_t + (size_t)hd * N_FFT;
        float ck, sk;
        __sincosf(-6.283185307179586f / 8192.f * (float)tid, &sk, &ck);
#pragma unroll
        for (int pp = 0; pp < 4; ++pp) {
            int k = pp * FT + tid;
            float x0 = src[k], x1 = src[k + 2048], x2 = src[k + 4096], x3 = src[k + 6144];
            float ar = x0 + x2, br = x0 - x2;
            float cr = x1 + x3, e = x1 - x3;
            re[PIDX(k)] = ar + cr; im[PIDX(k)] = 0.f;
            float c1 = ck, s1 = sk;
            float c2 = c1 * c1 - s1 * s1, s2 = 2.f * c1 * s1;
            float c3 = c2 * c1 - s2 * s1, s3 = c2 * s1 + s2 * c1;
            re[PIDX(k + 2048)] = br * c1 + e * s1;  im[PIDX(k + 2048)] = br * s1 - e * c1;
            float t2r = ar - cr;
            re[PIDX(k + 4096)] = t2r * c2;          im[PIDX(k + 4096)] = t2r * s2;
            re[PIDX(k + 6144)] = br * c3 - e * s3;  im[PIDX(k + 6144)] = br * s3 + e * c3;
            float tc = ck * JR - sk * JI; sk = ck * JI + sk * JR; ck = tc;  // W^{k+512}
        }
    }
    __syncthreads();
    pass16_fwd<2048>(re, im, tid);
    __syncthreads();
    pass16_fwd<128>(re, im, tid);
    __syncthreads();
    // ---- A tail: unscaled spectrum stays in registers (1/N folded in later) ----
    float afr[16], afi[16];
    {
        const int base = tid * 16;
#pragma unroll
        for (int c = 0; c < 16; ++c) { int idx = PIDX(base + c); afr[c] = re[idx]; afi[c] = im[idx]; }
        fwd8(afr, afi, 0); fwd8(afr, afi, 8);
    }
    __syncthreads();
    // ---- Z forward: fused m=8192 stage (packed complex, x2=x3=0) ----
    {
        const float2* src = xt2 + (size_t)hd * N_SEQ;
        float ck, sk;
        __sincosf(-6.283185307179586f / 8192.f * (float)tid, &sk, &ck);
#pragma unroll
        for (int pp = 0; pp < 4; ++pp) {
            int k = pp * FT + tid;
            float2 z0 = src[k], z1 = src[k + 2048];
            float ar = z0.x, ai = z0.y;
            float cr = z1.x, ci = z1.y;
            float dr = z1.y, di = -z1.x;
            re[PIDX(k)] = ar + cr; im[PIDX(k)] = ai + ci;
            float c1 = ck, s1 = sk;
            float c2 = c1 * c1 - s1 * s1, s2 = 2.f * c1 * s1;
            float c3 = c2 * c1 - s2 * s1, s3 = c2 * s1 + s2 * c1;
            float t1r = ar + dr, t1i = ai + di;
            re[PIDX(k + 2048)] = t1r * c1 - t1i * s1; im[PIDX(k + 2048)] = t1r * s1 + t1i * c1;
            float t2r = ar - cr, t2i = ai - ci;
            re[PIDX(k + 4096)] = t2r * c2 - t2i * s2; im[PIDX(k + 4096)] = t2r * s2 + t2i * c2;
            float t3r = ar - dr, t3i = ai - di;
            re[PIDX(k + 6144)] = t3r * c3 - t3i * s3; im[PIDX(k + 6144)] = t3r * s3 + t3i * c3;
            float tc = ck * JR - sk * JI; sk = ck * JI + sk * JR; ck = tc;
        }
    }
    __syncthreads();
    pass16_fwd<2048>(re, im, tid);
    __syncthreads();
    pass16_fwd<128>(re, im, tid);
    __syncthreads();
    {   // Z tail + pointwise (af in regs, 1/N fused) + inverse head
        const int base = tid * 16;
        float zr[16], zi[16];
#pragma unroll
        for (int c = 0; c < 16; ++c) { int idx = PIDX(base + c); zr[c] = re[idx]; zi[c] = im[idx]; }
        fwd8(zr, zi, 0); fwd8(zr, zi, 8);
        const float inv = 1.0f / (float)N_FFT;
#pragma unroll
        for (int c = 0; c < 16; ++c) {
            float xr = zr[c], xi_ = zi[c];
            zr[c] = (xr * afr[c] - xi_ * afi[c]) * inv;
            zi[c] = (xr * afi[c] + xi_ * afr[c]) * inv;
        }
        inv8(zr, zi, 0); inv8(zr, zi, 8);
#pragma unroll
        for (int c = 0; c < 16; ++c) { int idx = PIDX(base + c); re[idx] = zr[c]; im[idx] = zi[c]; }
    }
    __syncthreads();
    pass16_inv<128>(re, im, tid);
    __syncthreads();
    pass16_inv<2048>(re, im, tid);
    __syncthreads();
    {   // fused final inverse stage (m=8192): store only [0,4096)
        float2* dst = out_t2 + (size_t)hd * N_SEQ;
        float ck, sk;
        __sincosf(6.283185307179586f / 8192.f * (float)tid, &sk, &ck);
        const float JcR = 0.9238795325f, JcI = 0.3826834324f;
#pragma unroll
        for (int pp = 0; pp < 4; ++pp) {
            int k = pp * FT + tid;
            float c1 = ck, s1 = sk;
            float c2 = c1 * c1 - s1 * s1, s2 = 2.f * c1 * s1;
            float c3 = c2 * c1 - s2 * s1, s3 = c2 * s1 + s2 * c1;
            float t0r = re[PIDX(k)],        t0i = im[PIDX(k)];
            float y1r = re[PIDX(k + 2048)], y1i = im[PIDX(k + 2048)];
            float y2r = re[PIDX(k + 4096)], y2i = im[PIDX(k + 4096)];
            float y3r = re[PIDX(k + 6144)], y3i = im[PIDX(k + 6144)];
            float t1r = y1r * c1 - y1i * s1, t1i = y1r * s1 + y1i * c1;
            float t2r = y2r * c2 - y2i * s2, t2i = y2r * s2 + y2i * c2;
            float t3r = y3r * c3 - y3i * s3, t3i = y3r * s3 + y3i * c3;
            float pr = t0r + t2r, pi = t0i + t2i;
            float qr = t0r - t2r, qi = t0i - t2i;
            float rr = t1r + t3r, ri = t1i + t3i;
            float sr = -(t1i - t3i), si = t1r - t3r;
            dst[k]        = make_float2(pr + rr, pi + ri);
            dst[k + 2048] = make_float2(qr + sr, qi + si);
            float tc = ck * JcR - sk * JcI; sk = ck * JcI + sk * JcR; ck = tc;
        }
    }
}

// ========== transpose out: out_t2[hd][n] -> out (2,8,N,64) ==========
__global__ __launch_bounds__(256) void transpose_o_kernel(const float2* __restrict__ out_t2,
                                                          float* __restrict__ out)
{
    __shared__ float t0[64][65];
    __shared__ float t1[64][65];
    int h = blockIdx.x >> 6;
    int nb = blockIdx.x & 63;
    int lx = threadIdx.x & 63;
    int ly = threadIdx.x >> 6;
    for (int r = ly; r < 64; r += 4) {
        float2 v = out_t2[(size_t)(h * 64 + r) * N_SEQ + nb * 64 + lx];
        t0[r][lx] = v.x;
        t1[r][lx] = v.y;
    }
    __syncthreads();
    float* d0 = out + ((size_t)h * N_SEQ + nb * 64) * 64;
    float* d1 = out + ((size_t)(8 + h) * N_SEQ + nb * 64) * 64;
    for (int r = ly; r < 64; r += 4) {
        d0[r * 64 + lx] = t0[lx][r];
        d1[r * 64 + lx] = t1[lx][r];
    }
}

extern "C" void kernel_launch(void* const* d_in, const int* in_sizes, int n_in,
                              void* d_out, int out_size, void* d_ws, size_t ws_size,
                              hipStream_t stream)
{
    const float* x     = (const float*)d_in[0];
    const float* w_in  = (const float*)d_in[1];
    const float* b_in  = (const float*)d_in[2];
    const float* w_hid = (const float*)d_in[3];
    const float* b_hid = (const float*)d_in[4];
    const float* w_out = (const float*)d_in[5];
    const float* b_out = (const float*)d_in[6];
    float* out = (float*)d_out;

    char* ws = (char*)d_ws;
    float2* xt2    = (float2*)ws;                               // 16 MB
    float*  a_t    = (float*)(ws + (size_t)16 * 1024 * 1024);   // 16 MB
    float2* out_t2 = (float2*)(ws + (size_t)32 * 1024 * 1024);  // 16 MB

    prep_kernel<<<768, 512, 0, stream>>>(x, w_in, b_in, w_hid, b_hid, w_out, b_out,
                                         a_t, xt2);
    conv_kernel<<<512, FT, 0, stream>>>(a_t, xt2, out_t2);
    transpose_o_kernel<<<512, 256, 0, stream>>>(out_t2, out);
}